// Round 10
// baseline (413.450 us; speedup 1.0000x reference)
//
#include <hip/hip_runtime.h>
#include <math.h>

#define NN 50000
#define NBB 256
#define DD 128
#define FF 16
#define EE 800000
#define RR 15
#define EPSV 1e-7f
#define CSPACE (5.0f/14.0f)

__device__ __forceinline__ float lrelu(float x){ return x >= 0.f ? x : 0.01f*x; }
__device__ __forceinline__ float sigmoidf_(float x){ return 1.f/(1.f+expf(-x)); }

typedef __bf16 bf16x8 __attribute__((ext_vector_type(8)));
typedef float f32x4 __attribute__((ext_vector_type(4)));

__device__ __forceinline__ unsigned short f2bf(float x){
    union { float f; unsigned int u; } a; a.f = x;
    unsigned int r = (a.u + 0x7fffu + ((a.u >> 16) & 1u)) >> 16;
    return (unsigned short)r;
}
__device__ __forceinline__ unsigned int pack2(float a, float b){
    return (unsigned int)f2bf(a) | ((unsigned int)f2bf(b) << 16);
}
__device__ __forceinline__ float bf2f(unsigned short v){
    union { unsigned int u; float f; } a; a.u = ((unsigned int)v) << 16; return a.f;
}
__device__ __forceinline__ bf16x8 ld8(const unsigned short* p){
    union { uint4 u; bf16x8 b; } x; x.u = *(const uint4*)p; return x.b;
}

// ---------------- pack weights into MFMA B-fragment order (bf16) ----------------
__global__ void k_prep(const float* __restrict__ Wih, const float* __restrict__ Whh,
                       const float* __restrict__ Wq,
                       const float* __restrict__ phi1W, const float* __restrict__ phi2W,
                       const float* __restrict__ phi3W,
                       unsigned short* __restrict__ pWih, unsigned short* __restrict__ pWhh,
                       unsigned short* __restrict__ pWq,
                       unsigned short* __restrict__ pPhi1, unsigned short* __restrict__ pPhi2,
                       unsigned short* __restrict__ pPhi3){
    int i = blockIdx.x*256 + threadIdx.x;
    if (i < 3*8*8*64*8){
        int e = i&7, l=(i>>3)&63, kt=(i>>9)&7, c=(i>>12)&7, q=i>>15;
        int row = q*128 + c*16 + (l&15);
        int k = kt*32 + (l>>4)*8 + e;
        pWih[i] = f2bf(Wih[row*256 + k]);
    }
    if (i < 3*8*4*64*8){
        int e = i&7, l=(i>>3)&63, kt=(i>>9)&3, c=(i>>11)&7, q=i>>14;
        int row = q*128 + c*16 + (l&15);
        int k = kt*32 + (l>>4)*8 + e;
        pWhh[i] = f2bf(Whh[row*128 + k]);
    }
    if (i < 8*4*64*8){
        int e = i&7, l=(i>>3)&63, kt=(i>>9)&3, c=(i>>11)&7;
        pWq[i] = f2bf(Wq[(kt*32 + (l>>4)*8 + e)*DD + c*16 + (l&15)]);
    }
    if (i < 8*5*64*8){
        int e = i&7, l=(i>>3)&63;
        int t = i>>9;
        int kt = t%5, c = t/5;
        int k = kt*32 + (l>>4)*8 + e;
        int col = c*16 + (l&15);
        pPhi1[i] = f2bf(k < 144 ? phi1W[k*DD + col] : 0.f);
    }
    if (i < 5*64*8){
        int e = i&7, l=(i>>3)&63, kt = i>>9;
        int k = kt*32 + (l>>4)*8 + e;
        int col = l&15;
        pPhi2[i] = f2bf(k < 144 ? phi2W[k*FF + col] : 0.f);
    }
    if (i < 4*64*8){
        int e = i&7, l=(i>>3)&63, kt = i>>9;
        int k = kt*32 + (l>>4)*8 + e;
        int col = l&15;
        pPhi3[i] = f2bf(phi3W[k*FF + col]);
    }
}

// ---------------- fused per-node features: VN1/2/3 + phi1(hp) + phi2(hpp) + phi3*vn3(vp) ----------------
__global__ __launch_bounds__(512) void k_node(
    const float* __restrict__ hA, const float* __restrict__ vA,
    const float* __restrict__ vn1W, const float* __restrict__ vn1U,
    const float* __restrict__ vn2W, const float* __restrict__ vn2U,
    const float* __restrict__ vn3W, const float* __restrict__ vn3U,
    const unsigned short* __restrict__ pPhi1, const float* __restrict__ phi1b,
    const unsigned short* __restrict__ pPhi2, const float* __restrict__ phi2b,
    const unsigned short* __restrict__ pPhi3, const float* __restrict__ phi3b,
    float* __restrict__ hpO, float* __restrict__ hppO, float* __restrict__ vpO)
{
    __shared__ unsigned short sH[64*128];
    __shared__ unsigned short sE[64*64];
    __shared__ float sVA[64*48];
    __shared__ float sO3[64*16*3];
    __shared__ float sW[6*256];
    int tid = threadIdx.x;
    int n0 = blockIdx.x*64;

    #pragma unroll
    for (int it = 0; it < 2; ++it){
        int c = tid + it*512;
        int row = c >> 4, cb = c & 15;
        int gn = n0 + row; if (gn > NN-1) gn = NN-1;
        const float* p = hA + (size_t)gn*DD + cb*8;
        float4 f0 = *(const float4*)p;
        float4 f1 = *(const float4*)(p+4);
        uint4 u;
        u.x = pack2(f0.x,f0.y); u.y = pack2(f0.z,f0.w);
        u.z = pack2(f1.x,f1.y); u.w = pack2(f1.z,f1.w);
        *(uint4*)&sH[row*128 + ((cb ^ (row&7))*8)] = u;
    }
    #pragma unroll
    for (int it = 0; it < 6; ++it){
        int i = tid + it*512;
        int row = i/48, cc = i%48;
        int gn = n0 + row; if (gn > NN-1) gn = NN-1;
        sVA[i] = vA[(size_t)gn*48 + cc];
    }
    #pragma unroll
    for (int it = 0; it < 3; ++it){
        int i = tid + it*512;
        float v;
        if      (i <  256) v = vn1W[i];
        else if (i <  512) v = vn1U[i-256];
        else if (i <  768) v = vn2W[i-512];
        else if (i < 1024) v = vn2U[i-768];
        else if (i < 1280) v = vn3W[i-1024];
        else               v = vn3U[i-1280];
        sW[i] = v;
    }
    {
        uint2* z = (uint2*)sE;
        z[tid] = make_uint2(0u,0u);
        z[tid+512] = make_uint2(0u,0u);
    }
    __syncthreads();

    #pragma unroll
    for (int it = 0; it < 2; ++it){
        int item = tid + it*512;
        int nl = item >> 4, g = item & 15;
        const float* v = &sVA[nl*48];
        float q0[3]={0,0,0}, q1[3]={0,0,0}, q2[3]={0,0,0};
        float c0[3]={0,0,0}, c1[3]={0,0,0}, c2[3]={0,0,0};
        #pragma unroll
        for (int ff = 0; ff < FF; ++ff){
            int fi = (ff + g) & 15;
            float v0 = v[fi*3], v1 = v[fi*3+1], v2 = v[fi*3+2];
            #pragma unroll
            for (int m = 0; m < 3; ++m){
                float w = sW[m*512 + g*16 + fi];
                float u = sW[m*512 + 256 + g*16 + fi];
                q0[m] += w*v0; q1[m] += w*v1; q2[m] += w*v2;
                c0[m] += u*v0; c1[m] += u*v1; c2[m] += u*v2;
            }
        }
        #pragma unroll
        for (int m = 0; m < 3; ++m){
            float dot = q0[m]*c0[m] + q1[m]*c1[m] + q2[m]*c2[m];
            float ksq = c0[m]*c0[m] + c1[m]*c1[m] + c2[m]*c2[m] + EPSV;
            float s = dot >= 0.f ? 0.f : dot/ksq;
            float o0 = q0[m]-s*c0[m], o1 = q1[m]-s*c1[m], o2 = q2[m]-s*c2[m];
            if (m < 2){
                float nr = sqrtf(o0*o0+o1*o1+o2*o2) + EPSV;
                int col = (m==0) ? g : (32+g);
                int cb = col>>3;
                sE[nl*64 + ((cb ^ (nl&7))*8) + (col&7)] = f2bf(nr);
            } else {
                float* o = &sO3[(nl*16+g)*3];
                o[0]=o0; o[1]=o1; o[2]=o2;
            }
        }
    }
    __syncthreads();

    int wv = tid>>6, l = tid&63, lr = l&15, lg = l>>4;

    f32x4 a1[4];
    #pragma unroll
    for (int rt = 0; rt < 4; ++rt) a1[rt] = (f32x4){0.f,0.f,0.f,0.f};
    for (int kt = 0; kt < 4; ++kt){
        bf16x8 b = ld8(pPhi1 + ((size_t)(wv*5+kt)*64 + l)*8);
        #pragma unroll
        for (int rt = 0; rt < 4; ++rt){
            int row = rt*16 + lr;
            bf16x8 a = ld8(&sH[row*128 + (((kt*4+lg) ^ (row&7))*8)]);
            a1[rt] = __builtin_amdgcn_mfma_f32_16x16x32_bf16(a, b, a1[rt], 0, 0, 0);
        }
    }
    {
        bf16x8 b = ld8(pPhi1 + ((size_t)(wv*5+4)*64 + l)*8);
        #pragma unroll
        for (int rt = 0; rt < 4; ++rt){
            int row = rt*16 + lr;
            bf16x8 a = ld8(&sE[row*64 + ((lg ^ (row&7))*8)]);
            a1[rt] = __builtin_amdgcn_mfma_f32_16x16x32_bf16(a, b, a1[rt], 0, 0, 0);
        }
    }
    f32x4 a23 = (f32x4){0.f,0.f,0.f,0.f};
    if (wv < 4){
        int row = wv*16 + lr;
        for (int kt = 0; kt < 4; ++kt){
            bf16x8 b = ld8(pPhi3 + ((size_t)kt*64 + l)*8);
            bf16x8 a = ld8(&sH[row*128 + (((kt*4+lg) ^ (row&7))*8)]);
            a23 = __builtin_amdgcn_mfma_f32_16x16x32_bf16(a, b, a23, 0, 0, 0);
        }
    } else {
        int row = (wv-4)*16 + lr;
        for (int kt = 0; kt < 4; ++kt){
            bf16x8 b = ld8(pPhi2 + ((size_t)kt*64 + l)*8);
            bf16x8 a = ld8(&sH[row*128 + (((kt*4+lg) ^ (row&7))*8)]);
            a23 = __builtin_amdgcn_mfma_f32_16x16x32_bf16(a, b, a23, 0, 0, 0);
        }
        {
            bf16x8 b = ld8(pPhi2 + ((size_t)4*64 + l)*8);
            bf16x8 a = ld8(&sE[row*64 + (((4+lg) ^ (row&7))*8)]);
            a23 = __builtin_amdgcn_mfma_f32_16x16x32_bf16(a, b, a23, 0, 0, 0);
        }
    }

    {
        int col = wv*16 + lr;
        float b1 = phi1b[col];
        #pragma unroll
        for (int rt = 0; rt < 4; ++rt){
            #pragma unroll
            for (int r4 = 0; r4 < 4; ++r4){
                int n = n0 + rt*16 + lg*4 + r4;
                if (n < NN) hpO[(size_t)n*DD + col] = lrelu(a1[rt][r4] + b1);
            }
        }
    }
    if (wv < 4){
        float b3 = phi3b[lr];
        #pragma unroll
        for (int r4 = 0; r4 < 4; ++r4){
            int nl = wv*16 + lg*4 + r4;
            int n = n0 + nl;
            float gate = lrelu(a23[r4] + b3);
            if (n < NN){
                const float* o = &sO3[(nl*16+lr)*3];
                float* vo = vpO + (size_t)n*48 + lr*3;
                vo[0] = o[0]*gate; vo[1] = o[1]*gate; vo[2] = o[2]*gate;
            }
        }
    } else {
        float b2 = phi2b[lr];
        #pragma unroll
        for (int r4 = 0; r4 < 4; ++r4){
            int nl = (wv-4)*16 + lg*4 + r4;
            int n = n0 + nl;
            if (n < NN) hppO[(size_t)n*FF + lr] = lrelu(a23[r4] + b2);
        }
    }
}

// ---------------- kk/vv of h_B in MFMA B-fragment packed bf16 ----------------
__global__ __launch_bounds__(128) void k_kv(
    const float* __restrict__ hB, const float* __restrict__ Wk,
    const float* __restrict__ Wv, const float* __restrict__ bv,
    unsigned short* __restrict__ pKK, unsigned short* __restrict__ pVV)
{
    __shared__ float sB[DD];
    int b = blockIdx.x, j = threadIdx.x;
    sB[j] = hB[(size_t)b*DD + j];
    __syncthreads();
    float ak = 0.f, av = bv[j];
    for (int i = 0; i < DD; ++i){
        float h = sB[i];
        ak += h*Wk[i*DD+j];
        av += h*Wv[i*DD+j];
    }
    {
        int c = b>>4, lr = b&15, kt = j>>5, lg = (j>>3)&3, e = j&7;
        pKK[((c*4+kt)*64 + lg*16 + lr)*8 + e] = f2bf(lrelu(ak));
    }
    {
        int kt = b>>5, lg = (b>>3)&3, e = b&7, c = j>>4, lr = j&15;
        pVV[((c*8+kt)*64 + lg*16 + lr)*8 + e] = f2bf(av);
    }
}

// ---------------- FUSED attention + GRU, uncapped registers (no spill) ----------------
// 64 nodes/block, 512 thr = 8 waves. LDS 80KB -> occupancy is LDS-limited at
// 2 blocks/CU (= 4 waves/SIMD), which permits up to 512 VGPR/lane; the bare
// __launch_bounds__(512) cap of 128 VGPR only forced scratch spill (~72MB/launch).
__global__ __launch_bounds__(512, 1) void k_ag(
    const float* __restrict__ hA, const unsigned short* __restrict__ pWq,
    const unsigned short* __restrict__ pKK, const unsigned short* __restrict__ pVV,
    const float* __restrict__ mask,
    const float* __restrict__ hp, const float* __restrict__ acc,
    const float* __restrict__ Wr1, const float* __restrict__ br1,
    const unsigned short* __restrict__ pWih, const unsigned short* __restrict__ pWhh,
    const float* __restrict__ bih, const float* __restrict__ bhh,
    float* __restrict__ outNode)
{
    __shared__ unsigned short sXG[64*256];  // 32KB: [hA bf16 | attnO bf16], swizzled
    __shared__ unsigned short sP[64*256];   // 32KB: unnormalized P
    __shared__ unsigned short sQG[64*128];  // 16KB: Q -> softmax scratch overlay -> sGm
    int tid = threadIdx.x;
    int n0 = blockIdx.x*64;
    float* sMx = (float*)sQG;               // overlay [64][2] (Q dead when used)
    float* sSm = (float*)sQG + 128;         // overlay [64][2]

    // ---- phase 1: stage hA -> sXG cols 0..127
    #pragma unroll
    for (int it = 0; it < 2; ++it){
        int c = tid + it*512;
        int row = c >> 4, cb = c & 15;
        int gn = n0 + row; if (gn > NN-1) gn = NN-1;
        const float* p = hA + (size_t)gn*DD + cb*8;
        float4 f0 = *(const float4*)p;
        float4 f1 = *(const float4*)(p+4);
        uint4 u;
        u.x = pack2(f0.x,f0.y); u.y = pack2(f0.z,f0.w);
        u.z = pack2(f1.x,f1.y); u.w = pack2(f1.z,f1.w);
        *(uint4*)&sXG[row*256 + ((cb ^ (row&7))*8)] = u;
    }
    __syncthreads();

    int wv = tid>>6, l = tid&63, lr = l&15, lg = l>>4;
    int rw = wv>>1, chh = wv&1;
    int rowA = rw*16 + lr;

    // ---- phase 2: Q = lrelu(hA @ Wq) -> sQG
    {
        f32x4 q[4];
        #pragma unroll
        for (int c = 0; c < 4; ++c) q[c] = (f32x4){0.f,0.f,0.f,0.f};
        for (int kt = 0; kt < 4; ++kt){
            bf16x8 a = ld8(&sXG[rowA*256 + (((kt*4+lg) ^ (rowA&7))*8)]);
            #pragma unroll
            for (int c = 0; c < 4; ++c){
                bf16x8 b = ld8(pWq + (size_t)(((chh*4+c)*4 + kt)*512) + l*8);
                q[c] = __builtin_amdgcn_mfma_f32_16x16x32_bf16(a, b, q[c], 0, 0, 0);
            }
        }
        #pragma unroll
        for (int c = 0; c < 4; ++c)
        #pragma unroll
        for (int r4 = 0; r4 < 4; ++r4){
            int row = rw*16 + lg*4 + r4;
            int col = chh*64 + c*16 + lr;
            int cb = col>>3;
            sQG[row*128 + ((cb ^ (row&7))*8) + (col&7)] = f2bf(lrelu(q[c][r4]));
        }
    }
    __syncthreads();

    // ---- phase 3: S = Q @ kk^T; mask; softmax; P (unnormalized) -> sP. S dies here.
    float den[4];
    {
        f32x4 S[8];
        #pragma unroll
        for (int cl = 0; cl < 8; ++cl) S[cl] = (f32x4){0.f,0.f,0.f,0.f};
        for (int kt = 0; kt < 4; ++kt){
            bf16x8 a = ld8(&sQG[rowA*128 + (((kt*4+lg) ^ (rowA&7))*8)]);
            #pragma unroll
            for (int cl = 0; cl < 8; ++cl){
                bf16x8 b = ld8(pKK + (size_t)(((chh*8+cl)*4 + kt)*512) + l*8);
                S[cl] = __builtin_amdgcn_mfma_f32_16x16x32_bf16(a, b, S[cl], 0, 0, 0);
            }
        }
        float mx4[4];
        #pragma unroll
        for (int r4 = 0; r4 < 4; ++r4){
            int row = rw*16 + lg*4 + r4;
            int gn = n0 + row; if (gn > NN-1) gn = NN-1;
            float mx = -1e30f;
            #pragma unroll
            for (int cl = 0; cl < 8; ++cl){
                int col = chh*128 + cl*16 + lr;
                float m = mask[(size_t)gn*NBB + col];
                float s = m*S[cl][r4] - 1000.f*(1.f-m);
                S[cl][r4] = s;
                mx = fmaxf(mx, s);
            }
            mx = fmaxf(mx, __shfl_xor(mx, 1));
            mx = fmaxf(mx, __shfl_xor(mx, 2));
            mx = fmaxf(mx, __shfl_xor(mx, 4));
            mx = fmaxf(mx, __shfl_xor(mx, 8));
            mx4[r4] = mx;
        }
        __syncthreads();          // all QK^T sQG reads done -> overlay is safe
        #pragma unroll
        for (int r4 = 0; r4 < 4; ++r4){
            int row = rw*16 + lg*4 + r4;
            if (lr == 0) sMx[row*2+chh] = mx4[r4];
        }
        __syncthreads();
        #pragma unroll
        for (int r4 = 0; r4 < 4; ++r4){
            int row = rw*16 + lg*4 + r4;
            float m = fmaxf(sMx[row*2+0], sMx[row*2+1]);
            float sm = 0.f;
            #pragma unroll
            for (int cl = 0; cl < 8; ++cl){
                float p = expf(S[cl][r4] - m);
                int col = chh*128 + cl*16 + lr;
                int cb = col>>3;
                sP[row*256 + ((cb ^ (row&7))*8) + (col&7)] = f2bf(p);
                sm += p;
            }
            sm += __shfl_xor(sm, 1);
            sm += __shfl_xor(sm, 2);
            sm += __shfl_xor(sm, 4);
            sm += __shfl_xor(sm, 8);
            if (lr == 0) sSm[row*2+chh] = sm;
        }
        __syncthreads();
        #pragma unroll
        for (int r4 = 0; r4 < 4; ++r4){
            int row = rw*16 + lg*4 + r4;
            den[r4] = sSm[row*2+0] + sSm[row*2+1];
        }
    }
    __syncthreads();   // overlay reads done -> sGm staging may overwrite sQG

    // ---- phase 4: stage sGm (GRU hidden input) -> sQG
    #pragma unroll
    for (int it = 0; it < 2; ++it){
        int cc = tid + it*512;
        int row = cc >> 4, cb = cc & 15;
        int gn = n0 + row; if (gn > NN-1) gn = NN-1;
        int j = cb*8;
        const float* ar = acc + (size_t)gn*64;
        float cnt = ar[0];
        float dn = fmaxf(cnt, 1.f);
        float s[8];
        #pragma unroll
        for (int e = 0; e < 8; ++e) s[e] = cnt*br1[j+e];
        #pragma unroll
        for (int r = 0; r < RR; ++r){
            float av = ar[1+r];
            #pragma unroll
            for (int e = 0; e < 8; ++e) s[e] += av*Wr1[r*DD + j + e];
        }
        float4 h0 = *(const float4*)(hp + (size_t)gn*DD + j);
        float4 h1 = *(const float4*)(hp + (size_t)gn*DD + j + 4);
        float g0 = h0.x*s[0]/dn, g1 = h0.y*s[1]/dn, g2 = h0.z*s[2]/dn, g3 = h0.w*s[3]/dn;
        float g4 = h1.x*s[4]/dn, g5 = h1.y*s[5]/dn, g6 = h1.z*s[6]/dn, g7 = h1.w*s[7]/dn;
        uint4 u;
        u.x = pack2(g0,g1); u.y = pack2(g2,g3); u.z = pack2(g4,g5); u.w = pack2(g6,g7);
        *(uint4*)&sQG[row*128 + ((cb ^ (row&7))*8)] = u;
    }
    __syncthreads();

    // ---- phase 5: O = P @ vv -> bf16 O/den into sXG cols 128..255
    {
        f32x4 O[4];
        #pragma unroll
        for (int c = 0; c < 4; ++c) O[c] = (f32x4){0.f,0.f,0.f,0.f};
        for (int kt = 0; kt < 8; ++kt){
            bf16x8 a = ld8(&sP[rowA*256 + (((kt*4+lg) ^ (rowA&7))*8)]);
            #pragma unroll
            for (int c = 0; c < 4; ++c){
                bf16x8 b = ld8(pVV + (size_t)(((chh*4+c)*8 + kt)*512) + l*8);
                O[c] = __builtin_amdgcn_mfma_f32_16x16x32_bf16(a, b, O[c], 0, 0, 0);
            }
        }
        #pragma unroll
        for (int c = 0; c < 4; ++c)
        #pragma unroll
        for (int r4 = 0; r4 < 4; ++r4){
            int row = rw*16 + lg*4 + r4;
            int colg = 128 + chh*64 + c*16 + lr;
            int cb = colg>>3;
            sXG[row*256 + ((cb ^ (row&7))*8) + (colg&7)] = f2bf(O[c][r4] / den[r4]);
        }
    }
    __syncthreads();

    // ---- phase 6: GRU GEMMs + epilogue
    f32x4 aR[4], aZ[4], aNI[4], aNH[4];
    #pragma unroll
    for (int rt = 0; rt < 4; ++rt){
        aR[rt] = (f32x4){0.f,0.f,0.f,0.f};
        aZ[rt] = (f32x4){0.f,0.f,0.f,0.f};
        aNI[rt] = (f32x4){0.f,0.f,0.f,0.f};
        aNH[rt] = (f32x4){0.f,0.f,0.f,0.f};
    }
    const unsigned short* bR = pWih + ((size_t)(0*8 + wv)*8)*512 + l*8;
    const unsigned short* bZ = pWih + ((size_t)(1*8 + wv)*8)*512 + l*8;
    const unsigned short* bN = pWih + ((size_t)(2*8 + wv)*8)*512 + l*8;
    for (int kt = 0; kt < 8; ++kt){
        bf16x8 br_ = ld8(bR + kt*512);
        bf16x8 bz_ = ld8(bZ + kt*512);
        bf16x8 bn_ = ld8(bN + kt*512);
        #pragma unroll
        for (int rt = 0; rt < 4; ++rt){
            int rA = rt*16 + lr;
            bf16x8 a = ld8(&sXG[rA*256 + (((kt*4 + lg) ^ (rA&7))*8)]);
            aR[rt]  = __builtin_amdgcn_mfma_f32_16x16x32_bf16(a, br_, aR[rt], 0, 0, 0);
            aZ[rt]  = __builtin_amdgcn_mfma_f32_16x16x32_bf16(a, bz_, aZ[rt], 0, 0, 0);
            aNI[rt] = __builtin_amdgcn_mfma_f32_16x16x32_bf16(a, bn_, aNI[rt], 0, 0, 0);
        }
    }
    const unsigned short* cR = pWhh + ((size_t)(0*8 + wv)*4)*512 + l*8;
    const unsigned short* cZ = pWhh + ((size_t)(1*8 + wv)*4)*512 + l*8;
    const unsigned short* cN = pWhh + ((size_t)(2*8 + wv)*4)*512 + l*8;
    for (int kt = 0; kt < 4; ++kt){
        bf16x8 br_ = ld8(cR + kt*512);
        bf16x8 bz_ = ld8(cZ + kt*512);
        bf16x8 bn_ = ld8(cN + kt*512);
        #pragma unroll
        for (int rt = 0; rt < 4; ++rt){
            int rA = rt*16 + lr;
            bf16x8 a = ld8(&sQG[rA*128 + (((kt*4 + lg) ^ (rA&7))*8)]);
            aR[rt]  = __builtin_amdgcn_mfma_f32_16x16x32_bf16(a, br_, aR[rt], 0, 0, 0);
            aZ[rt]  = __builtin_amdgcn_mfma_f32_16x16x32_bf16(a, bz_, aZ[rt], 0, 0, 0);
            aNH[rt] = __builtin_amdgcn_mfma_f32_16x16x32_bf16(a, bn_, aNH[rt], 0, 0, 0);
        }
    }
    int col = wv*16 + lr;
    float b_r = bih[col] + bhh[col];
    float b_z = bih[DD+col] + bhh[DD+col];
    float b_ni = bih[2*DD+col];
    float b_nh = bhh[2*DD+col];
    #pragma unroll
    for (int rt = 0; rt < 4; ++rt){
        #pragma unroll
        for (int r4 = 0; r4 < 4; ++r4){
            int nl = rt*16 + lg*4 + r4;
            int n = n0 + nl;
            if (n < NN){
                float rg = sigmoidf_(aR[rt][r4] + b_r);
                float zg = sigmoidf_(aZ[rt][r4] + b_z);
                float ng = tanhf(aNI[rt][r4] + b_ni + rg*(aNH[rt][r4] + b_nh));
                float sg = bf2f(sQG[nl*128 + (((col>>3) ^ (nl&7))*8) + (col&7)]);
                float h = hA[(size_t)n*DD + col];
                outNode[(size_t)n*DD + col] = h + (1.f-zg)*ng + zg*sg;
            }
        }
    }
}

// ---------------- edge phase: counting sort by dst, then per-node gather ----------------
__global__ __launch_bounds__(256) void k_hist(const int* __restrict__ dst, int* __restrict__ deg){
    int e = blockIdx.x*256 + threadIdx.x;
    if (e < EE) atomicAdd(&deg[dst[e]], 1);
}

__global__ __launch_bounds__(256) void k_scan1(const int* __restrict__ deg,
                                               int* __restrict__ excl, int* __restrict__ bsum){
    __shared__ int s[256];
    int tid = threadIdx.x;
    int i = blockIdx.x*256 + tid;
    int v = (i < NN) ? deg[i] : 0;
    s[tid] = v;
    __syncthreads();
    for (int o = 1; o < 256; o <<= 1){
        int t = 0;
        if (tid >= o) t = s[tid-o];
        __syncthreads();
        if (tid >= o) s[tid] += t;
        __syncthreads();
    }
    if (i < NN) excl[i] = s[tid] - v;
    if (tid == 255) bsum[blockIdx.x] = s[255];
}

__global__ __launch_bounds__(256) void k_scan2(const int* __restrict__ bsum,
                                               int* __restrict__ boff, int nb){
    __shared__ int s[256];
    int tid = threadIdx.x;
    int v = (tid < nb) ? bsum[tid] : 0;
    s[tid] = v;
    __syncthreads();
    for (int o = 1; o < 256; o <<= 1){
        int t = 0;
        if (tid >= o) t = s[tid-o];
        __syncthreads();
        if (tid >= o) s[tid] += t;
        __syncthreads();
    }
    if (tid < nb) boff[tid] = s[tid] - v;
}

__global__ __launch_bounds__(256) void k_scan3(const int* __restrict__ excl,
                                               const int* __restrict__ boff,
                                               int* __restrict__ start, int* __restrict__ cursor){
    int i = blockIdx.x*256 + threadIdx.x;
    if (i < NN){
        int st = excl[i] + boff[blockIdx.x];
        start[i] = st;
        cursor[i] = st;
    }
    if (i == 0) start[NN] = EE;
}

__global__ __launch_bounds__(256) void k_scatter(const int* __restrict__ src,
                                                 const int* __restrict__ dst,
                                                 int* __restrict__ cursor, int* __restrict__ esrc){
    int e = blockIdx.x*256 + threadIdx.x;
    if (e >= EE) return;
    int pos = atomicAdd(&cursor[dst[e]], 1);
    esrc[pos] = src[e];
}

// 4 lanes per node, butterfly-reduced
__global__ __launch_bounds__(256) void k_gather(const int* __restrict__ start,
                                                const int* __restrict__ esrc,
                                                const float* __restrict__ xA,
                                                const float* __restrict__ rbf_k,
                                                float* __restrict__ acc)
{
    int gt = blockIdx.x*256 + threadIdx.x;
    int n = gt >> 2, sub = gt & 3;
    if (n >= NN) return;
    float kc = rbf_k[0];
    float xd0 = xA[n*3+0], xd1 = xA[n*3+1], xd2 = xA[n*3+2];
    float a[64];
    #pragma unroll
    for (int i = 0; i < 64; ++i) a[i] = 0.f;
    int b0 = start[n], b1 = start[n+1];
    for (int i = b0 + sub; i < b1; i += 4){
        int s = esrc[i];
        float r0 = xA[s*3+0]-xd0, r1 = xA[s*3+1]-xd1, r2 = xA[s*3+2]-xd2;
        float rn = sqrtf(r0*r0+r1*r1+r2*r2);
        a[0] += 1.f;
        a[16] += r0; a[17] += r1; a[18] += r2;
        #pragma unroll
        for (int q = 0; q < RR; ++q){
            float df = rn - (float)q*CSPACE;
            float rb = expf(-df*df*kc);
            a[1+q] += rb;
            a[19+q*3+0] += rb*r0;
            a[19+q*3+1] += rb*r1;
            a[19+q*3+2] += rb*r2;
        }
    }
    #pragma unroll
    for (int i = 0; i < 64; ++i){
        a[i] += __shfl_xor(a[i], 1);
        a[i] += __shfl_xor(a[i], 2);
    }
    float4* o = (float4*)(acc + (size_t)n*64);
    #pragma unroll
    for (int i = 0; i < 4; ++i){
        int idx = sub*4 + i;
        o[idx] = make_float4(a[4*idx], a[4*idx+1], a[4*idx+2], a[4*idx+3]);
    }
}

// ---------------- vector update: agg_v inline, VN-MLP, residual ----------------
__global__ __launch_bounds__(256) void k_vec(
    const float* __restrict__ vA, const float* __restrict__ vp,
    const float* __restrict__ hpp, const float* __restrict__ acc,
    const float* __restrict__ Wr2, const float* __restrict__ br2,
    const float* __restrict__ Wr3, const float* __restrict__ br3,
    const float* __restrict__ W1, const float* __restrict__ U1,
    const float* __restrict__ W2, float* __restrict__ outV)
{
    __shared__ float sW1[32*32], sU1[32*32], sW2[16*32];
    __shared__ float sWr2[RR*FF], sWr3[RR*FF];
    __shared__ float sVin[8][32][3];
    __shared__ float sVh[8][32][3];
    __shared__ float sAcc[8][64];
    __shared__ float sVA[8][48];
    int tid = threadIdx.x;
    for (int i = tid; i < 1024; i += 256){ sW1[i]=W1[i]; sU1[i]=U1[i]; }
    for (int i = tid; i < 512; i += 256) sW2[i]=W2[i];
    for (int i = tid; i < RR*FF; i += 256){ sWr2[i]=Wr2[i]; sWr3[i]=Wr3[i]; }
    int n0 = blockIdx.x*8;
    for (int i = tid; i < 8*64; i += 256) sAcc[i/64][i%64] = acc[(size_t)n0*64 + i];
    for (int i = tid; i < 8*48; i += 256) sVA[i/48][i%48] = vA[(size_t)n0*48 + i];
    __syncthreads();
    int t = tid >> 5, g = tid & 31;
    int n = n0 + t;
    if (g < 16){
        int f = g;
        float cnt = sAcc[t][0];
        float den = fmaxf(cnt, 1.f);
        float s1 = cnt*br2[f];
        #pragma unroll
        for (int r = 0; r < RR; ++r) s1 += sAcc[t][1+r]*sWr2[r*FF+f];
        float hpv = hpp[(size_t)n*FF+f];
        float b3 = br3[f];
        #pragma unroll
        for (int c = 0; c < 3; ++c){
            float s2 = b3*sAcc[t][16+c];
            #pragma unroll
            for (int r = 0; r < RR; ++r) s2 += sAcc[t][19+r*3+c]*sWr3[r*FF+f];
            float aggv = (vp[(size_t)n*48 + f*3 + c]*s1 + hpv*s2)/den;
            sVin[t][FF+f][c] = aggv;
            sVin[t][f][c] = sVA[t][f*3+c];
        }
    }
    __syncthreads();
    {
        float q0=0,q1=0,q2=0,k0=0,k1=0,k2=0;
        #pragma unroll
        for (int ff = 0; ff < 32; ++ff){
            int f = (ff + g) & 31;
            float w = sW1[g*32+f], u = sU1[g*32+f];
            float v0=sVin[t][f][0], v1=sVin[t][f][1], v2=sVin[t][f][2];
            q0+=w*v0;q1+=w*v1;q2+=w*v2;
            k0+=u*v0;k1+=u*v1;k2+=u*v2;
        }
        float dot=q0*k0+q1*k1+q2*k2;
        float ksq=k0*k0+k1*k1+k2*k2+EPSV;
        float s = dot>=0.f?0.f:dot/ksq;
        sVh[t][g][0]=q0-s*k0; sVh[t][g][1]=q1-s*k1; sVh[t][g][2]=q2-s*k2;
    }
    __syncthreads();
    if (g < 16){
        float o0=sVA[t][g*3+0], o1=sVA[t][g*3+1], o2=sVA[t][g*3+2];
        #pragma unroll
        for (int ff = 0; ff < 32; ++ff){
            int f = (ff + g) & 31;
            float w = sW2[g*32+f];
            o0 += w*sVh[t][f][0];
            o1 += w*sVh[t][f][1];
            o2 += w*sVh[t][f][2];
        }
        outV[(size_t)n*48 + g*3 + 0] = o0;
        outV[(size_t)n*48 + g*3 + 1] = o1;
        outV[(size_t)n*48 + g*3 + 2] = o2;
    }
}

extern "C" void kernel_launch(void* const* d_in, const int* in_sizes, int n_in,
                              void* d_out, int out_size, void* d_ws, size_t ws_size,
                              hipStream_t stream)
{
    const float* hA   = (const float*)d_in[0];
    const float* vA   = (const float*)d_in[1];
    const float* xA   = (const float*)d_in[2];
    const float* hB   = (const float*)d_in[3];
    const float* mask = (const float*)d_in[4];
    const int*   src  = (const int*)d_in[5];
    const int*   dst  = (const int*)d_in[6];
    const float* rbfk = (const float*)d_in[7];
    const float* Wr1  = (const float*)d_in[8];
    const float* br1  = (const float*)d_in[9];
    const float* Wr2  = (const float*)d_in[10];
    const float* br2  = (const float*)d_in[11];
    const float* Wr3  = (const float*)d_in[12];
    const float* br3  = (const float*)d_in[13];
    const float* vn1W = (const float*)d_in[14];
    const float* vn1U = (const float*)d_in[15];
    const float* vn2W = (const float*)d_in[16];
    const float* vn2U = (const float*)d_in[17];
    const float* vn3W = (const float*)d_in[18];
    const float* vn3U = (const float*)d_in[19];
    const float* phi1W= (const float*)d_in[20];
    const float* phi1b= (const float*)d_in[21];
    const float* phi2W= (const float*)d_in[22];
    const float* phi2b= (const float*)d_in[23];
    const float* phi3W= (const float*)d_in[24];
    const float* phi3b= (const float*)d_in[25];
    const float* Wq   = (const float*)d_in[26];
    const float* Wk   = (const float*)d_in[27];
    const float* Wv   = (const float*)d_in[28];
    const float* bv   = (const float*)d_in[29];
    const float* Wih  = (const float*)d_in[30];
    const float* Whh  = (const float*)d_in[31];
    const float* bih  = (const float*)d_in[32];
    const float* bhh  = (const float*)d_in[33];
    const float* W1   = (const float*)d_in[34];
    const float* U1   = (const float*)d_in[35];
    const float* W2   = (const float*)d_in[36];

    float* ws = (float*)d_ws;
    float* hp     = ws;  ws += (size_t)NN*DD;
    float* hpp    = ws;  ws += (size_t)NN*FF;
    float* vp     = ws;  ws += (size_t)NN*FF*3;
    float* acc    = ws;  ws += (size_t)NN*64;
    unsigned short* pWih = (unsigned short*)ws; ws += (size_t)3*8*8*512/2;
    unsigned short* pWhh = (unsigned short*)ws; ws += (size_t)3*8*4*512/2;
    unsigned short* pWq  = (unsigned short*)ws; ws += (size_t)8*4*512/2;
    unsigned short* pKK  = (unsigned short*)ws; ws += (size_t)16*4*512/2;
    unsigned short* pVV  = (unsigned short*)ws; ws += (size_t)8*8*512/2;
    unsigned short* pPhi1= (unsigned short*)ws; ws += (size_t)8*5*512/2;
    unsigned short* pPhi2= (unsigned short*)ws; ws += (size_t)5*512/2;
    unsigned short* pPhi3= (unsigned short*)ws; ws += (size_t)4*512/2;
    int* deg    = (int*)ws;  ws += NN;
    int* excl   = (int*)ws;  ws += NN;
    int* bsum   = (int*)ws;  ws += 256;
    int* boff   = (int*)ws;  ws += 256;
    int* startN = (int*)ws;  ws += NN+1;
    int* cursor = (int*)ws;  ws += NN;
    int* esrc   = (int*)ws;  ws += EE;

    float* outV = (float*)d_out;
    float* outH = (float*)d_out + (size_t)NN*FF*3;

    const int NB_SCAN = (NN + 255)/256;

    hipMemsetAsync(deg, 0, (size_t)NN*sizeof(int), stream);
    k_prep<<<384, 256, 0, stream>>>(Wih, Whh, Wq, phi1W, phi2W, phi3W,
                                    pWih, pWhh, pWq, pPhi1, pPhi2, pPhi3);
    k_hist<<<(EE+255)/256, 256, 0, stream>>>(dst, deg);
    k_scan1<<<NB_SCAN, 256, 0, stream>>>(deg, excl, bsum);
    k_scan2<<<1, 256, 0, stream>>>(bsum, boff, NB_SCAN);
    k_scan3<<<NB_SCAN, 256, 0, stream>>>(excl, boff, startN, cursor);
    k_scatter<<<(EE+255)/256, 256, 0, stream>>>(src, dst, cursor, esrc);
    k_gather<<<(NN*4+255)/256, 256, 0, stream>>>(startN, esrc, xA, rbfk, acc);
    k_node<<<(NN+63)/64, 512, 0, stream>>>(hA, vA, vn1W, vn1U, vn2W, vn2U, vn3W, vn3U,
                                           pPhi1, phi1b, pPhi2, phi2b, pPhi3, phi3b,
                                           hp, hpp, vp);
    k_kv<<<NBB, 128, 0, stream>>>(hB, Wk, Wv, bv, pKK, pVV);
    k_ag<<<(NN+63)/64, 512, 0, stream>>>(hA, pWq, pKK, pVV, mask, hp, acc, Wr1, br1,
                                         pWih, pWhh, bih, bhh, outH);
    k_vec<<<NN/8, 256, 0, stream>>>(vA, vp, hpp, acc, Wr2, br2, Wr3, br3, W1, U1, W2, outV);
}

// Round 11
// 373.048 us; speedup vs baseline: 1.1083x; 1.1083x over previous
//
#include <hip/hip_runtime.h>
#include <math.h>

#define NN 50000
#define NBB 256
#define DD 128
#define FF 16
#define EE 800000
#define RR 15
#define EPSV 1e-7f
#define CSPACE (5.0f/14.0f)

__device__ __forceinline__ float lrelu(float x){ return x >= 0.f ? x : 0.01f*x; }
__device__ __forceinline__ float sigmoidf_(float x){ return 1.f/(1.f+expf(-x)); }

typedef __bf16 bf16x8 __attribute__((ext_vector_type(8)));
typedef float f32x4 __attribute__((ext_vector_type(4)));

__device__ __forceinline__ unsigned short f2bf(float x){
    union { float f; unsigned int u; } a; a.f = x;
    unsigned int r = (a.u + 0x7fffu + ((a.u >> 16) & 1u)) >> 16;
    return (unsigned short)r;
}
__device__ __forceinline__ unsigned int pack2(float a, float b){
    return (unsigned int)f2bf(a) | ((unsigned int)f2bf(b) << 16);
}
__device__ __forceinline__ float bf2f(unsigned short v){
    union { unsigned int u; float f; } a; a.u = ((unsigned int)v) << 16; return a.f;
}
__device__ __forceinline__ bf16x8 ld8(const unsigned short* p){
    union { uint4 u; bf16x8 b; } x; x.u = *(const uint4*)p; return x.b;
}

// ---------------- pack weights into MFMA B-fragment order (bf16) ----------------
__global__ void k_prep(const float* __restrict__ Wih, const float* __restrict__ Whh,
                       const float* __restrict__ Wq,
                       const float* __restrict__ phi1W, const float* __restrict__ phi2W,
                       const float* __restrict__ phi3W,
                       unsigned short* __restrict__ pWih, unsigned short* __restrict__ pWhh,
                       unsigned short* __restrict__ pWq,
                       unsigned short* __restrict__ pPhi1, unsigned short* __restrict__ pPhi2,
                       unsigned short* __restrict__ pPhi3){
    int i = blockIdx.x*256 + threadIdx.x;
    if (i < 3*8*8*64*8){
        int e = i&7, l=(i>>3)&63, kt=(i>>9)&7, c=(i>>12)&7, q=i>>15;
        int row = q*128 + c*16 + (l&15);
        int k = kt*32 + (l>>4)*8 + e;
        pWih[i] = f2bf(Wih[row*256 + k]);
    }
    if (i < 3*8*4*64*8){
        int e = i&7, l=(i>>3)&63, kt=(i>>9)&3, c=(i>>11)&7, q=i>>14;
        int row = q*128 + c*16 + (l&15);
        int k = kt*32 + (l>>4)*8 + e;
        pWhh[i] = f2bf(Whh[row*128 + k]);
    }
    if (i < 8*4*64*8){
        int e = i&7, l=(i>>3)&63, kt=(i>>9)&3, c=(i>>11)&7;
        pWq[i] = f2bf(Wq[(kt*32 + (l>>4)*8 + e)*DD + c*16 + (l&15)]);
    }
    if (i < 8*5*64*8){
        int e = i&7, l=(i>>3)&63;
        int t = i>>9;
        int kt = t%5, c = t/5;
        int k = kt*32 + (l>>4)*8 + e;
        int col = c*16 + (l&15);
        pPhi1[i] = f2bf(k < 144 ? phi1W[k*DD + col] : 0.f);
    }
    if (i < 5*64*8){
        int e = i&7, l=(i>>3)&63, kt = i>>9;
        int k = kt*32 + (l>>4)*8 + e;
        int col = l&15;
        pPhi2[i] = f2bf(k < 144 ? phi2W[k*FF + col] : 0.f);
    }
    if (i < 4*64*8){
        int e = i&7, l=(i>>3)&63, kt = i>>9;
        int k = kt*32 + (l>>4)*8 + e;
        int col = l&15;
        pPhi3[i] = f2bf(phi3W[k*FF + col]);
    }
}

// ---------------- fused per-node features: VN1/2/3 + phi1(hp) + phi2(hpp) + phi3*vn3(vp) ----------------
__global__ __launch_bounds__(512) void k_node(
    const float* __restrict__ hA, const float* __restrict__ vA,
    const float* __restrict__ vn1W, const float* __restrict__ vn1U,
    const float* __restrict__ vn2W, const float* __restrict__ vn2U,
    const float* __restrict__ vn3W, const float* __restrict__ vn3U,
    const unsigned short* __restrict__ pPhi1, const float* __restrict__ phi1b,
    const unsigned short* __restrict__ pPhi2, const float* __restrict__ phi2b,
    const unsigned short* __restrict__ pPhi3, const float* __restrict__ phi3b,
    float* __restrict__ hpO, float* __restrict__ hppO, float* __restrict__ vpO)
{
    __shared__ unsigned short sH[64*128];
    __shared__ unsigned short sE[64*64];
    __shared__ float sVA[64*48];
    __shared__ float sO3[64*16*3];
    __shared__ float sW[6*256];
    int tid = threadIdx.x;
    int n0 = blockIdx.x*64;

    #pragma unroll
    for (int it = 0; it < 2; ++it){
        int c = tid + it*512;
        int row = c >> 4, cb = c & 15;
        int gn = n0 + row; if (gn > NN-1) gn = NN-1;
        const float* p = hA + (size_t)gn*DD + cb*8;
        float4 f0 = *(const float4*)p;
        float4 f1 = *(const float4*)(p+4);
        uint4 u;
        u.x = pack2(f0.x,f0.y); u.y = pack2(f0.z,f0.w);
        u.z = pack2(f1.x,f1.y); u.w = pack2(f1.z,f1.w);
        *(uint4*)&sH[row*128 + ((cb ^ (row&7))*8)] = u;
    }
    #pragma unroll
    for (int it = 0; it < 6; ++it){
        int i = tid + it*512;
        int row = i/48, cc = i%48;
        int gn = n0 + row; if (gn > NN-1) gn = NN-1;
        sVA[i] = vA[(size_t)gn*48 + cc];
    }
    #pragma unroll
    for (int it = 0; it < 3; ++it){
        int i = tid + it*512;
        float v;
        if      (i <  256) v = vn1W[i];
        else if (i <  512) v = vn1U[i-256];
        else if (i <  768) v = vn2W[i-512];
        else if (i < 1024) v = vn2U[i-768];
        else if (i < 1280) v = vn3W[i-1024];
        else               v = vn3U[i-1280];
        sW[i] = v;
    }
    {
        uint2* z = (uint2*)sE;
        z[tid] = make_uint2(0u,0u);
        z[tid+512] = make_uint2(0u,0u);
    }
    __syncthreads();

    #pragma unroll
    for (int it = 0; it < 2; ++it){
        int item = tid + it*512;
        int nl = item >> 4, g = item & 15;
        const float* v = &sVA[nl*48];
        float q0[3]={0,0,0}, q1[3]={0,0,0}, q2[3]={0,0,0};
        float c0[3]={0,0,0}, c1[3]={0,0,0}, c2[3]={0,0,0};
        #pragma unroll
        for (int ff = 0; ff < FF; ++ff){
            int fi = (ff + g) & 15;
            float v0 = v[fi*3], v1 = v[fi*3+1], v2 = v[fi*3+2];
            #pragma unroll
            for (int m = 0; m < 3; ++m){
                float w = sW[m*512 + g*16 + fi];
                float u = sW[m*512 + 256 + g*16 + fi];
                q0[m] += w*v0; q1[m] += w*v1; q2[m] += w*v2;
                c0[m] += u*v0; c1[m] += u*v1; c2[m] += u*v2;
            }
        }
        #pragma unroll
        for (int m = 0; m < 3; ++m){
            float dot = q0[m]*c0[m] + q1[m]*c1[m] + q2[m]*c2[m];
            float ksq = c0[m]*c0[m] + c1[m]*c1[m] + c2[m]*c2[m] + EPSV;
            float s = dot >= 0.f ? 0.f : dot/ksq;
            float o0 = q0[m]-s*c0[m], o1 = q1[m]-s*c1[m], o2 = q2[m]-s*c2[m];
            if (m < 2){
                float nr = sqrtf(o0*o0+o1*o1+o2*o2) + EPSV;
                int col = (m==0) ? g : (32+g);
                int cb = col>>3;
                sE[nl*64 + ((cb ^ (nl&7))*8) + (col&7)] = f2bf(nr);
            } else {
                float* o = &sO3[(nl*16+g)*3];
                o[0]=o0; o[1]=o1; o[2]=o2;
            }
        }
    }
    __syncthreads();

    int wv = tid>>6, l = tid&63, lr = l&15, lg = l>>4;

    f32x4 a1[4];
    #pragma unroll
    for (int rt = 0; rt < 4; ++rt) a1[rt] = (f32x4){0.f,0.f,0.f,0.f};
    for (int kt = 0; kt < 4; ++kt){
        bf16x8 b = ld8(pPhi1 + ((size_t)(wv*5+kt)*64 + l)*8);
        #pragma unroll
        for (int rt = 0; rt < 4; ++rt){
            int row = rt*16 + lr;
            bf16x8 a = ld8(&sH[row*128 + (((kt*4+lg) ^ (row&7))*8)]);
            a1[rt] = __builtin_amdgcn_mfma_f32_16x16x32_bf16(a, b, a1[rt], 0, 0, 0);
        }
    }
    {
        bf16x8 b = ld8(pPhi1 + ((size_t)(wv*5+4)*64 + l)*8);
        #pragma unroll
        for (int rt = 0; rt < 4; ++rt){
            int row = rt*16 + lr;
            bf16x8 a = ld8(&sE[row*64 + ((lg ^ (row&7))*8)]);
            a1[rt] = __builtin_amdgcn_mfma_f32_16x16x32_bf16(a, b, a1[rt], 0, 0, 0);
        }
    }
    f32x4 a23 = (f32x4){0.f,0.f,0.f,0.f};
    if (wv < 4){
        int row = wv*16 + lr;
        for (int kt = 0; kt < 4; ++kt){
            bf16x8 b = ld8(pPhi3 + ((size_t)kt*64 + l)*8);
            bf16x8 a = ld8(&sH[row*128 + (((kt*4+lg) ^ (row&7))*8)]);
            a23 = __builtin_amdgcn_mfma_f32_16x16x32_bf16(a, b, a23, 0, 0, 0);
        }
    } else {
        int row = (wv-4)*16 + lr;
        for (int kt = 0; kt < 4; ++kt){
            bf16x8 b = ld8(pPhi2 + ((size_t)kt*64 + l)*8);
            bf16x8 a = ld8(&sH[row*128 + (((kt*4+lg) ^ (row&7))*8)]);
            a23 = __builtin_amdgcn_mfma_f32_16x16x32_bf16(a, b, a23, 0, 0, 0);
        }
        {
            bf16x8 b = ld8(pPhi2 + ((size_t)4*64 + l)*8);
            bf16x8 a = ld8(&sE[row*64 + (((4+lg) ^ (row&7))*8)]);
            a23 = __builtin_amdgcn_mfma_f32_16x16x32_bf16(a, b, a23, 0, 0, 0);
        }
    }

    {
        int col = wv*16 + lr;
        float b1 = phi1b[col];
        #pragma unroll
        for (int rt = 0; rt < 4; ++rt){
            #pragma unroll
            for (int r4 = 0; r4 < 4; ++r4){
                int n = n0 + rt*16 + lg*4 + r4;
                if (n < NN) hpO[(size_t)n*DD + col] = lrelu(a1[rt][r4] + b1);
            }
        }
    }
    if (wv < 4){
        float b3 = phi3b[lr];
        #pragma unroll
        for (int r4 = 0; r4 < 4; ++r4){
            int nl = wv*16 + lg*4 + r4;
            int n = n0 + nl;
            float gate = lrelu(a23[r4] + b3);
            if (n < NN){
                const float* o = &sO3[(nl*16+lr)*3];
                float* vo = vpO + (size_t)n*48 + lr*3;
                vo[0] = o[0]*gate; vo[1] = o[1]*gate; vo[2] = o[2]*gate;
            }
        }
    } else {
        float b2 = phi2b[lr];
        #pragma unroll
        for (int r4 = 0; r4 < 4; ++r4){
            int nl = (wv-4)*16 + lg*4 + r4;
            int n = n0 + nl;
            if (n < NN) hppO[(size_t)n*FF + lr] = lrelu(a23[r4] + b2);
        }
    }
}

// ---------------- kk/vv of h_B in MFMA B-fragment packed bf16 ----------------
__global__ __launch_bounds__(128) void k_kv(
    const float* __restrict__ hB, const float* __restrict__ Wk,
    const float* __restrict__ Wv, const float* __restrict__ bv,
    unsigned short* __restrict__ pKK, unsigned short* __restrict__ pVV)
{
    __shared__ float sB[DD];
    int b = blockIdx.x, j = threadIdx.x;
    sB[j] = hB[(size_t)b*DD + j];
    __syncthreads();
    float ak = 0.f, av = bv[j];
    for (int i = 0; i < DD; ++i){
        float h = sB[i];
        ak += h*Wk[i*DD+j];
        av += h*Wv[i*DD+j];
    }
    {
        int c = b>>4, lr = b&15, kt = j>>5, lg = (j>>3)&3, e = j&7;
        pKK[((c*4+kt)*64 + lg*16 + lr)*8 + e] = f2bf(lrelu(ak));
    }
    {
        int kt = b>>5, lg = (b>>3)&3, e = b&7, c = j>>4, lr = j&15;
        pVV[((c*8+kt)*64 + lg*16 + lr)*8 + e] = f2bf(av);
    }
}

// ---------------- fused cross-attention via bf16 MFMA ----------------
__global__ __launch_bounds__(512, 4) void k_attn_mfma(
    const float* __restrict__ hA, const unsigned short* __restrict__ pWq,
    const unsigned short* __restrict__ pKK, const unsigned short* __restrict__ pVV,
    const float* __restrict__ mask, float* __restrict__ attnO)
{
    __shared__ unsigned short sU[64*256];
    __shared__ float sMx[64][2];
    __shared__ float sSm[64][2];
    unsigned short* sX = sU;
    unsigned short* sQ = sU + 64*128;
    unsigned short* sP = sU;
    int tid = threadIdx.x;
    int n0 = blockIdx.x*64;

    #pragma unroll
    for (int it = 0; it < 2; ++it){
        int c = tid + it*512;
        int row = c >> 4, cb = c & 15;
        int gn = n0 + row; if (gn > NN-1) gn = NN-1;
        const float* srcp = hA + (size_t)gn*DD + cb*8;
        float4 f0 = *(const float4*)srcp;
        float4 f1 = *(const float4*)(srcp+4);
        uint4 u;
        u.x = pack2(f0.x,f0.y); u.y = pack2(f0.z,f0.w);
        u.z = pack2(f1.x,f1.y); u.w = pack2(f1.z,f1.w);
        *(uint4*)&sX[row*128 + ((cb ^ (row&7))*8)] = u;
    }
    __syncthreads();

    int wv = tid>>6, l = tid&63, lr = l&15, lg = l>>4;
    int rw = wv>>1, chh = wv&1;
    int rowA = rw*16 + lr;

    {
        f32x4 q[4];
        #pragma unroll
        for (int c = 0; c < 4; ++c) q[c] = (f32x4){0.f,0.f,0.f,0.f};
        for (int kt = 0; kt < 4; ++kt){
            bf16x8 a = ld8(&sX[rowA*128 + (((kt*4+lg) ^ (rowA&7))*8)]);
            #pragma unroll
            for (int c = 0; c < 4; ++c){
                bf16x8 b = ld8(pWq + (size_t)(((chh*4+c)*4 + kt)*512) + l*8);
                q[c] = __builtin_amdgcn_mfma_f32_16x16x32_bf16(a, b, q[c], 0, 0, 0);
            }
        }
        __syncthreads();
        #pragma unroll
        for (int c = 0; c < 4; ++c)
        #pragma unroll
        for (int r4 = 0; r4 < 4; ++r4){
            int row = rw*16 + lg*4 + r4;
            int col = chh*64 + c*16 + lr;
            int cb = col>>3;
            sQ[row*128 + ((cb ^ (row&7))*8) + (col&7)] = f2bf(lrelu(q[c][r4]));
        }
    }
    __syncthreads();

    f32x4 S[8];
    #pragma unroll
    for (int cl = 0; cl < 8; ++cl) S[cl] = (f32x4){0.f,0.f,0.f,0.f};
    for (int kt = 0; kt < 4; ++kt){
        bf16x8 a = ld8(&sQ[rowA*128 + (((kt*4+lg) ^ (rowA&7))*8)]);
        #pragma unroll
        for (int cl = 0; cl < 8; ++cl){
            bf16x8 b = ld8(pKK + (size_t)(((chh*8+cl)*4 + kt)*512) + l*8);
            S[cl] = __builtin_amdgcn_mfma_f32_16x16x32_bf16(a, b, S[cl], 0, 0, 0);
        }
    }
    float den[4];
    #pragma unroll
    for (int r4 = 0; r4 < 4; ++r4){
        int row = rw*16 + lg*4 + r4;
        int gn = n0 + row; if (gn > NN-1) gn = NN-1;
        float mx = -1e30f;
        #pragma unroll
        for (int cl = 0; cl < 8; ++cl){
            int col = chh*128 + cl*16 + lr;
            float m = mask[(size_t)gn*NBB + col];
            float s = m*S[cl][r4] - 1000.f*(1.f-m);
            S[cl][r4] = s;
            mx = fmaxf(mx, s);
        }
        mx = fmaxf(mx, __shfl_xor(mx, 1));
        mx = fmaxf(mx, __shfl_xor(mx, 2));
        mx = fmaxf(mx, __shfl_xor(mx, 4));
        mx = fmaxf(mx, __shfl_xor(mx, 8));
        if (lr == 0) sMx[row][chh] = mx;
    }
    __syncthreads();
    #pragma unroll
    for (int r4 = 0; r4 < 4; ++r4){
        int row = rw*16 + lg*4 + r4;
        float m = fmaxf(sMx[row][0], sMx[row][1]);
        float sm = 0.f;
        #pragma unroll
        for (int cl = 0; cl < 8; ++cl){
            float p = expf(S[cl][r4] - m);
            S[cl][r4] = p;
            sm += p;
        }
        sm += __shfl_xor(sm, 1);
        sm += __shfl_xor(sm, 2);
        sm += __shfl_xor(sm, 4);
        sm += __shfl_xor(sm, 8);
        if (lr == 0) sSm[row][chh] = sm;
    }
    __syncthreads();
    #pragma unroll
    for (int r4 = 0; r4 < 4; ++r4){
        int row = rw*16 + lg*4 + r4;
        den[r4] = sSm[row][0] + sSm[row][1];
    }
    #pragma unroll
    for (int cl = 0; cl < 8; ++cl)
    #pragma unroll
    for (int r4 = 0; r4 < 4; ++r4){
        int row = rw*16 + lg*4 + r4;
        int col = chh*128 + cl*16 + lr;
        int cb = col>>3;
        sP[row*256 + ((cb ^ (row&7))*8) + (col&7)] = f2bf(S[cl][r4]);
    }
    __syncthreads();

    f32x4 O[4];
    #pragma unroll
    for (int c = 0; c < 4; ++c) O[c] = (f32x4){0.f,0.f,0.f,0.f};
    for (int kt = 0; kt < 8; ++kt){
        bf16x8 a = ld8(&sP[rowA*256 + (((kt*4+lg) ^ (rowA&7))*8)]);
        #pragma unroll
        for (int c = 0; c < 4; ++c){
            bf16x8 b = ld8(pVV + (size_t)(((chh*4+c)*8 + kt)*512) + l*8);
            O[c] = __builtin_amdgcn_mfma_f32_16x16x32_bf16(a, b, O[c], 0, 0, 0);
        }
    }
    #pragma unroll
    for (int c = 0; c < 4; ++c)
    #pragma unroll
    for (int r4 = 0; r4 < 4; ++r4){
        int row = rw*16 + lg*4 + r4;
        int n = n0 + row;
        if (n < NN){
            int col = chh*64 + c*16 + lr;
            attnO[(size_t)n*DD + col] = O[c][r4] / den[r4];
        }
    }
}

// ---------------- edge phase: counting sort by dst, then per-node gather ----------------
__global__ __launch_bounds__(256) void k_hist(const int* __restrict__ dst, int* __restrict__ deg){
    int e = blockIdx.x*256 + threadIdx.x;
    if (e < EE) atomicAdd(&deg[dst[e]], 1);
}

__global__ __launch_bounds__(256) void k_scan1(const int* __restrict__ deg,
                                               int* __restrict__ excl, int* __restrict__ bsum){
    __shared__ int s[256];
    int tid = threadIdx.x;
    int i = blockIdx.x*256 + tid;
    int v = (i < NN) ? deg[i] : 0;
    s[tid] = v;
    __syncthreads();
    for (int o = 1; o < 256; o <<= 1){
        int t = 0;
        if (tid >= o) t = s[tid-o];
        __syncthreads();
        if (tid >= o) s[tid] += t;
        __syncthreads();
    }
    if (i < NN) excl[i] = s[tid] - v;
    if (tid == 255) bsum[blockIdx.x] = s[255];
}

__global__ __launch_bounds__(256) void k_scan2(const int* __restrict__ bsum,
                                               int* __restrict__ boff, int nb){
    __shared__ int s[256];
    int tid = threadIdx.x;
    int v = (tid < nb) ? bsum[tid] : 0;
    s[tid] = v;
    __syncthreads();
    for (int o = 1; o < 256; o <<= 1){
        int t = 0;
        if (tid >= o) t = s[tid-o];
        __syncthreads();
        if (tid >= o) s[tid] += t;
        __syncthreads();
    }
    if (tid < nb) boff[tid] = s[tid] - v;
}

__global__ __launch_bounds__(256) void k_scan3(const int* __restrict__ excl,
                                               const int* __restrict__ boff,
                                               int* __restrict__ start, int* __restrict__ cursor){
    int i = blockIdx.x*256 + threadIdx.x;
    if (i < NN){
        int st = excl[i] + boff[blockIdx.x];
        start[i] = st;
        cursor[i] = st;
    }
    if (i == 0) start[NN] = EE;
}

__global__ __launch_bounds__(256) void k_scatter(const int* __restrict__ src,
                                                 const int* __restrict__ dst,
                                                 int* __restrict__ cursor, int* __restrict__ esrc){
    int e = blockIdx.x*256 + threadIdx.x;
    if (e >= EE) return;
    int pos = atomicAdd(&cursor[dst[e]], 1);
    esrc[pos] = src[e];
}

// 4 lanes per node, butterfly-reduced
__global__ __launch_bounds__(256) void k_gather(const int* __restrict__ start,
                                                const int* __restrict__ esrc,
                                                const float* __restrict__ xA,
                                                const float* __restrict__ rbf_k,
                                                float* __restrict__ acc)
{
    int gt = blockIdx.x*256 + threadIdx.x;
    int n = gt >> 2, sub = gt & 3;
    if (n >= NN) return;
    float kc = rbf_k[0];
    float xd0 = xA[n*3+0], xd1 = xA[n*3+1], xd2 = xA[n*3+2];
    float a[64];
    #pragma unroll
    for (int i = 0; i < 64; ++i) a[i] = 0.f;
    int b0 = start[n], b1 = start[n+1];
    for (int i = b0 + sub; i < b1; i += 4){
        int s = esrc[i];
        float r0 = xA[s*3+0]-xd0, r1 = xA[s*3+1]-xd1, r2 = xA[s*3+2]-xd2;
        float rn = sqrtf(r0*r0+r1*r1+r2*r2);
        a[0] += 1.f;
        a[16] += r0; a[17] += r1; a[18] += r2;
        #pragma unroll
        for (int q = 0; q < RR; ++q){
            float df = rn - (float)q*CSPACE;
            float rb = expf(-df*df*kc);
            a[1+q] += rb;
            a[19+q*3+0] += rb*r0;
            a[19+q*3+1] += rb*r1;
            a[19+q*3+2] += rb*r2;
        }
    }
    #pragma unroll
    for (int i = 0; i < 64; ++i){
        a[i] += __shfl_xor(a[i], 1);
        a[i] += __shfl_xor(a[i], 2);
    }
    float4* o = (float4*)(acc + (size_t)n*64);
    #pragma unroll
    for (int i = 0; i < 4; ++i){
        int idx = sub*4 + i;
        o[idx] = make_float4(a[4*idx], a[4*idx+1], a[4*idx+2], a[4*idx+3]);
    }
}

// ---------------- GRU via bf16 MFMA, packed-fragment weights ----------------
__global__ __launch_bounds__(512) void k_gru_mfma(
    const float* __restrict__ hA, const float* __restrict__ attn,
    const float* __restrict__ hp, const float* __restrict__ acc,
    const float* __restrict__ Wr1, const float* __restrict__ br1,
    const unsigned short* __restrict__ pWih, const unsigned short* __restrict__ pWhh,
    const float* __restrict__ bih, const float* __restrict__ bhh,
    float* __restrict__ outNode)
{
    __shared__ unsigned short sX[64*256];
    __shared__ unsigned short sGm[64*128];
    int tid = threadIdx.x;
    int n0 = blockIdx.x*64;

    #pragma unroll
    for (int it = 0; it < 4; ++it){
        int c = tid + it*512;
        int row = c >> 5, cb = c & 31;
        int gn = n0 + row; if (gn > NN-1) gn = NN-1;
        int k = cb*8;
        const float* srcp = (k < DD) ? (hA + (size_t)gn*DD + k)
                                     : (attn + (size_t)gn*DD + (k-DD));
        float4 f0 = *(const float4*)srcp;
        float4 f1 = *(const float4*)(srcp+4);
        uint4 u;
        u.x = pack2(f0.x,f0.y); u.y = pack2(f0.z,f0.w);
        u.z = pack2(f1.x,f1.y); u.w = pack2(f1.z,f1.w);
        *(uint4*)&sX[row*256 + ((cb ^ (row&7))*8)] = u;
    }
    #pragma unroll
    for (int it = 0; it < 2; ++it){
        int c = tid + it*512;
        int row = c >> 4, cb = c & 15;
        int gn = n0 + row; if (gn > NN-1) gn = NN-1;
        int j = cb*8;
        const float* ar = acc + (size_t)gn*64;
        float cnt = ar[0];
        float den = fmaxf(cnt, 1.f);
        float s[8];
        #pragma unroll
        for (int e = 0; e < 8; ++e) s[e] = cnt*br1[j+e];
        #pragma unroll
        for (int r = 0; r < RR; ++r){
            float av = ar[1+r];
            #pragma unroll
            for (int e = 0; e < 8; ++e) s[e] += av*Wr1[r*DD + j + e];
        }
        float4 h0 = *(const float4*)(hp + (size_t)gn*DD + j);
        float4 h1 = *(const float4*)(hp + (size_t)gn*DD + j + 4);
        float g0 = h0.x*s[0]/den, g1 = h0.y*s[1]/den, g2 = h0.z*s[2]/den, g3 = h0.w*s[3]/den;
        float g4 = h1.x*s[4]/den, g5 = h1.y*s[5]/den, g6 = h1.z*s[6]/den, g7 = h1.w*s[7]/den;
        uint4 u;
        u.x = pack2(g0,g1); u.y = pack2(g2,g3); u.z = pack2(g4,g5); u.w = pack2(g6,g7);
        *(uint4*)&sGm[row*128 + ((cb ^ (row&7))*8)] = u;
    }
    __syncthreads();

    int wv = tid >> 6, l = tid & 63;
    int lr = l & 15, lg = l >> 4;

    f32x4 aR[4], aZ[4], aNI[4], aNH[4];
    #pragma unroll
    for (int rt = 0; rt < 4; ++rt){
        aR[rt] = (f32x4){0.f,0.f,0.f,0.f};
        aZ[rt] = (f32x4){0.f,0.f,0.f,0.f};
        aNI[rt] = (f32x4){0.f,0.f,0.f,0.f};
        aNH[rt] = (f32x4){0.f,0.f,0.f,0.f};
    }

    const unsigned short* bR = pWih + ((size_t)(0*8 + wv)*8)*512 + l*8;
    const unsigned short* bZ = pWih + ((size_t)(1*8 + wv)*8)*512 + l*8;
    const unsigned short* bN = pWih + ((size_t)(2*8 + wv)*8)*512 + l*8;
    for (int kt = 0; kt < 8; ++kt){
        bf16x8 br_ = ld8(bR + kt*512);
        bf16x8 bz_ = ld8(bZ + kt*512);
        bf16x8 bn_ = ld8(bN + kt*512);
        #pragma unroll
        for (int rt = 0; rt < 4; ++rt){
            int rowA = rt*16 + lr;
            bf16x8 a = ld8(&sX[rowA*256 + (((kt*4 + lg) ^ (rowA&7))*8)]);
            aR[rt]  = __builtin_amdgcn_mfma_f32_16x16x32_bf16(a, br_, aR[rt], 0, 0, 0);
            aZ[rt]  = __builtin_amdgcn_mfma_f32_16x16x32_bf16(a, bz_, aZ[rt], 0, 0, 0);
            aNI[rt] = __builtin_amdgcn_mfma_f32_16x16x32_bf16(a, bn_, aNI[rt], 0, 0, 0);
        }
    }
    const unsigned short* cR = pWhh + ((size_t)(0*8 + wv)*4)*512 + l*8;
    const unsigned short* cZ = pWhh + ((size_t)(1*8 + wv)*4)*512 + l*8;
    const unsigned short* cN = pWhh + ((size_t)(2*8 + wv)*4)*512 + l*8;
    for (int kt = 0; kt < 4; ++kt){
        bf16x8 br_ = ld8(cR + kt*512);
        bf16x8 bz_ = ld8(cZ + kt*512);
        bf16x8 bn_ = ld8(cN + kt*512);
        #pragma unroll
        for (int rt = 0; rt < 4; ++rt){
            int rowA = rt*16 + lr;
            bf16x8 a = ld8(&sGm[rowA*128 + (((kt*4 + lg) ^ (rowA&7))*8)]);
            aR[rt]  = __builtin_amdgcn_mfma_f32_16x16x32_bf16(a, br_, aR[rt], 0, 0, 0);
            aZ[rt]  = __builtin_amdgcn_mfma_f32_16x16x32_bf16(a, bz_, aZ[rt], 0, 0, 0);
            aNH[rt] = __builtin_amdgcn_mfma_f32_16x16x32_bf16(a, bn_, aNH[rt], 0, 0, 0);
        }
    }

    int col = wv*16 + lr;
    float b_r = bih[col] + bhh[col];
    float b_z = bih[DD+col] + bhh[DD+col];
    float b_ni = bih[2*DD+col];
    float b_nh = bhh[2*DD+col];
    #pragma unroll
    for (int rt = 0; rt < 4; ++rt){
        #pragma unroll
        for (int r4 = 0; r4 < 4; ++r4){
            int nl = rt*16 + lg*4 + r4;
            int n = n0 + nl;
            if (n < NN){
                float rg = sigmoidf_(aR[rt][r4] + b_r);
                float zg = sigmoidf_(aZ[rt][r4] + b_z);
                float ng = tanhf(aNI[rt][r4] + b_ni + rg*(aNH[rt][r4] + b_nh));
                float sg = bf2f(sGm[nl*128 + (((col>>3) ^ (nl&7))*8) + (col&7)]);
                float h = hA[(size_t)n*DD + col];
                outNode[(size_t)n*DD + col] = h + (1.f-zg)*ng + zg*sg;
            }
        }
    }
}

// ---------------- vector update: agg_v inline, VN-MLP, residual ----------------
__global__ __launch_bounds__(256) void k_vec(
    const float* __restrict__ vA, const float* __restrict__ vp,
    const float* __restrict__ hpp, const float* __restrict__ acc,
    const float* __restrict__ Wr2, const float* __restrict__ br2,
    const float* __restrict__ Wr3, const float* __restrict__ br3,
    const float* __restrict__ W1, const float* __restrict__ U1,
    const float* __restrict__ W2, float* __restrict__ outV)
{
    __shared__ float sW1[32*32], sU1[32*32], sW2[16*32];
    __shared__ float sWr2[RR*FF], sWr3[RR*FF];
    __shared__ float sVin[8][32][3];
    __shared__ float sVh[8][32][3];
    __shared__ float sAcc[8][64];
    __shared__ float sVA[8][48];
    int tid = threadIdx.x;
    for (int i = tid; i < 1024; i += 256){ sW1[i]=W1[i]; sU1[i]=U1[i]; }
    for (int i = tid; i < 512; i += 256) sW2[i]=W2[i];
    for (int i = tid; i < RR*FF; i += 256){ sWr2[i]=Wr2[i]; sWr3[i]=Wr3[i]; }
    int n0 = blockIdx.x*8;
    for (int i = tid; i < 8*64; i += 256) sAcc[i/64][i%64] = acc[(size_t)n0*64 + i];
    for (int i = tid; i < 8*48; i += 256) sVA[i/48][i%48] = vA[(size_t)n0*48 + i];
    __syncthreads();
    int t = tid >> 5, g = tid & 31;
    int n = n0 + t;
    if (g < 16){
        int f = g;
        float cnt = sAcc[t][0];
        float den = fmaxf(cnt, 1.f);
        float s1 = cnt*br2[f];
        #pragma unroll
        for (int r = 0; r < RR; ++r) s1 += sAcc[t][1+r]*sWr2[r*FF+f];
        float hpv = hpp[(size_t)n*FF+f];
        float b3 = br3[f];
        #pragma unroll
        for (int c = 0; c < 3; ++c){
            float s2 = b3*sAcc[t][16+c];
            #pragma unroll
            for (int r = 0; r < RR; ++r) s2 += sAcc[t][19+r*3+c]*sWr3[r*FF+f];
            float aggv = (vp[(size_t)n*48 + f*3 + c]*s1 + hpv*s2)/den;
            sVin[t][FF+f][c] = aggv;
            sVin[t][f][c] = sVA[t][f*3+c];
        }
    }
    __syncthreads();
    {
        float q0=0,q1=0,q2=0,k0=0,k1=0,k2=0;
        #pragma unroll
        for (int ff = 0; ff < 32; ++ff){
            int f = (ff + g) & 31;
            float w = sW1[g*32+f], u = sU1[g*32+f];
            float v0=sVin[t][f][0], v1=sVin[t][f][1], v2=sVin[t][f][2];
            q0+=w*v0;q1+=w*v1;q2+=w*v2;
            k0+=u*v0;k1+=u*v1;k2+=u*v2;
        }
        float dot=q0*k0+q1*k1+q2*k2;
        float ksq=k0*k0+k1*k1+k2*k2+EPSV;
        float s = dot>=0.f?0.f:dot/ksq;
        sVh[t][g][0]=q0-s*k0; sVh[t][g][1]=q1-s*k1; sVh[t][g][2]=q2-s*k2;
    }
    __syncthreads();
    if (g < 16){
        float o0=sVA[t][g*3+0], o1=sVA[t][g*3+1], o2=sVA[t][g*3+2];
        #pragma unroll
        for (int ff = 0; ff < 32; ++ff){
            int f = (ff + g) & 31;
            float w = sW2[g*32+f];
            o0 += w*sVh[t][f][0];
            o1 += w*sVh[t][f][1];
            o2 += w*sVh[t][f][2];
        }
        outV[(size_t)n*48 + g*3 + 0] = o0;
        outV[(size_t)n*48 + g*3 + 1] = o1;
        outV[(size_t)n*48 + g*3 + 2] = o2;
    }
}

extern "C" void kernel_launch(void* const* d_in, const int* in_sizes, int n_in,
                              void* d_out, int out_size, void* d_ws, size_t ws_size,
                              hipStream_t stream)
{
    const float* hA   = (const float*)d_in[0];
    const float* vA   = (const float*)d_in[1];
    const float* xA   = (const float*)d_in[2];
    const float* hB   = (const float*)d_in[3];
    const float* mask = (const float*)d_in[4];
    const int*   src  = (const int*)d_in[5];
    const int*   dst  = (const int*)d_in[6];
    const float* rbfk = (const float*)d_in[7];
    const float* Wr1  = (const float*)d_in[8];
    const float* br1  = (const float*)d_in[9];
    const float* Wr2  = (const float*)d_in[10];
    const float* br2  = (const float*)d_in[11];
    const float* Wr3  = (const float*)d_in[12];
    const float* br3  = (const float*)d_in[13];
    const float* vn1W = (const float*)d_in[14];
    const float* vn1U = (const float*)d_in[15];
    const float* vn2W = (const float*)d_in[16];
    const float* vn2U = (const float*)d_in[17];
    const float* vn3W = (const float*)d_in[18];
    const float* vn3U = (const float*)d_in[19];
    const float* phi1W= (const float*)d_in[20];
    const float* phi1b= (const float*)d_in[21];
    const float* phi2W= (const float*)d_in[22];
    const float* phi2b= (const float*)d_in[23];
    const float* phi3W= (const float*)d_in[24];
    const float* phi3b= (const float*)d_in[25];
    const float* Wq   = (const float*)d_in[26];
    const float* Wk   = (const float*)d_in[27];
    const float* Wv   = (const float*)d_in[28];
    const float* bv   = (const float*)d_in[29];
    const float* Wih  = (const float*)d_in[30];
    const float* Whh  = (const float*)d_in[31];
    const float* bih  = (const float*)d_in[32];
    const float* bhh  = (const float*)d_in[33];
    const float* W1   = (const float*)d_in[34];
    const float* U1   = (const float*)d_in[35];
    const float* W2   = (const float*)d_in[36];

    float* ws = (float*)d_ws;
    float* hp     = ws;  ws += (size_t)NN*DD;
    float* hpp    = ws;  ws += (size_t)NN*FF;
    float* vp     = ws;  ws += (size_t)NN*FF*3;
    float* attn   = ws;  ws += (size_t)NN*DD;
    float* acc    = ws;  ws += (size_t)NN*64;
    unsigned short* pWih = (unsigned short*)ws; ws += (size_t)3*8*8*512/2;
    unsigned short* pWhh = (unsigned short*)ws; ws += (size_t)3*8*4*512/2;
    unsigned short* pWq  = (unsigned short*)ws; ws += (size_t)8*4*512/2;
    unsigned short* pKK  = (unsigned short*)ws; ws += (size_t)16*4*512/2;
    unsigned short* pVV  = (unsigned short*)ws; ws += (size_t)8*8*512/2;
    unsigned short* pPhi1= (unsigned short*)ws; ws += (size_t)8*5*512/2;
    unsigned short* pPhi2= (unsigned short*)ws; ws += (size_t)5*512/2;
    unsigned short* pPhi3= (unsigned short*)ws; ws += (size_t)4*512/2;
    int* deg    = (int*)ws;  ws += NN;
    int* excl   = (int*)ws;  ws += NN;
    int* bsum   = (int*)ws;  ws += 256;
    int* boff   = (int*)ws;  ws += 256;
    int* startN = (int*)ws;  ws += NN+1;
    int* cursor = (int*)ws;  ws += NN;
    int* esrc   = (int*)ws;  ws += EE;

    float* outV = (float*)d_out;
    float* outH = (float*)d_out + (size_t)NN*FF*3;

    const int NB_SCAN = (NN + 255)/256;

    hipMemsetAsync(deg, 0, (size_t)NN*sizeof(int), stream);
    k_prep<<<384, 256, 0, stream>>>(Wih, Whh, Wq, phi1W, phi2W, phi3W,
                                    pWih, pWhh, pWq, pPhi1, pPhi2, pPhi3);
    k_hist<<<(EE+255)/256, 256, 0, stream>>>(dst, deg);
    k_scan1<<<NB_SCAN, 256, 0, stream>>>(deg, excl, bsum);
    k_scan2<<<1, 256, 0, stream>>>(bsum, boff, NB_SCAN);
    k_scan3<<<NB_SCAN, 256, 0, stream>>>(excl, boff, startN, cursor);
    k_scatter<<<(EE+255)/256, 256, 0, stream>>>(src, dst, cursor, esrc);
    k_gather<<<(NN*4+255)/256, 256, 0, stream>>>(startN, esrc, xA, rbfk, acc);
    k_node<<<(NN+63)/64, 512, 0, stream>>>(hA, vA, vn1W, vn1U, vn2W, vn2U, vn3W, vn3U,
                                           pPhi1, phi1b, pPhi2, phi2b, pPhi3, phi3b,
                                           hp, hpp, vp);
    k_kv<<<NBB, 128, 0, stream>>>(hB, Wk, Wv, bv, pKK, pVV);
    k_attn_mfma<<<(NN+63)/64, 512, 0, stream>>>(hA, pWq, pKK, pVV, mask, attn);
    k_gru_mfma<<<(NN+63)/64, 512, 0, stream>>>(hA, attn, hp, acc, Wr1, br1,
                                               pWih, pWhh, bih, bhh, outH);
    k_vec<<<NN/8, 256, 0, stream>>>(vA, vp, hpp, acc, Wr2, br2, Wr3, br3, W1, U1, W2, outV);
}

// Round 12
// 344.090 us; speedup vs baseline: 1.2016x; 1.0842x over previous
//
#include <hip/hip_runtime.h>
#include <math.h>

#define NN 50000
#define NBB 256
#define DD 128
#define FF 16
#define EE 800000
#define RR 15
#define EPSV 1e-7f
#define CSPACE (5.0f/14.0f)

__device__ __forceinline__ float lrelu(float x){ return x >= 0.f ? x : 0.01f*x; }
__device__ __forceinline__ float sigmoidf_(float x){ return 1.f/(1.f+expf(-x)); }

typedef __bf16 bf16x8 __attribute__((ext_vector_type(8)));
typedef float f32x4 __attribute__((ext_vector_type(4)));

__device__ __forceinline__ unsigned short f2bf(float x){
    union { float f; unsigned int u; } a; a.f = x;
    unsigned int r = (a.u + 0x7fffu + ((a.u >> 16) & 1u)) >> 16;
    return (unsigned short)r;
}
__device__ __forceinline__ unsigned int pack2(float a, float b){
    return (unsigned int)f2bf(a) | ((unsigned int)f2bf(b) << 16);
}
__device__ __forceinline__ float bf2f(unsigned short v){
    union { unsigned int u; float f; } a; a.u = ((unsigned int)v) << 16; return a.f;
}
__device__ __forceinline__ bf16x8 ld8(const unsigned short* p){
    union { uint4 u; bf16x8 b; } x; x.u = *(const uint4*)p; return x.b;
}

// ---------------- pack weights into MFMA B-fragment order (bf16) ----------------
__global__ void k_prep(const float* __restrict__ Wih, const float* __restrict__ Whh,
                       const float* __restrict__ Wq,
                       const float* __restrict__ phi1W, const float* __restrict__ phi2W,
                       const float* __restrict__ phi3W,
                       const float* __restrict__ Wr1, const float* __restrict__ br1,
                       unsigned short* __restrict__ pWih, unsigned short* __restrict__ pWhh,
                       unsigned short* __restrict__ pWq,
                       unsigned short* __restrict__ pPhi1, unsigned short* __restrict__ pPhi2,
                       unsigned short* __restrict__ pPhi3, unsigned short* __restrict__ pWr1){
    int i = blockIdx.x*256 + threadIdx.x;
    if (i < 3*8*8*64*8){
        int e = i&7, l=(i>>3)&63, kt=(i>>9)&7, c=(i>>12)&7, q=i>>15;
        int row = q*128 + c*16 + (l&15);
        int k = kt*32 + (l>>4)*8 + e;
        pWih[i] = f2bf(Wih[row*256 + k]);
    }
    if (i < 3*8*4*64*8){
        int e = i&7, l=(i>>3)&63, kt=(i>>9)&3, c=(i>>11)&7, q=i>>14;
        int row = q*128 + c*16 + (l&15);
        int k = kt*32 + (l>>4)*8 + e;
        pWhh[i] = f2bf(Whh[row*128 + k]);
    }
    if (i < 8*4*64*8){
        int e = i&7, l=(i>>3)&63, kt=(i>>9)&3, c=(i>>11)&7;
        pWq[i] = f2bf(Wq[(kt*32 + (l>>4)*8 + e)*DD + c*16 + (l&15)]);
    }
    if (i < 8*5*64*8){
        int e = i&7, l=(i>>3)&63;
        int t = i>>9;
        int kt = t%5, c = t/5;
        int k = kt*32 + (l>>4)*8 + e;
        int col = c*16 + (l&15);
        pPhi1[i] = f2bf(k < 144 ? phi1W[k*DD + col] : 0.f);
    }
    if (i < 5*64*8){
        int e = i&7, l=(i>>3)&63, kt = i>>9;
        int k = kt*32 + (l>>4)*8 + e;
        int col = l&15;
        pPhi2[i] = f2bf(k < 144 ? phi2W[k*FF + col] : 0.f);
    }
    if (i < 4*64*8){
        int e = i&7, l=(i>>3)&63, kt = i>>9;
        int k = kt*32 + (l>>4)*8 + e;
        int col = l&15;
        pPhi3[i] = f2bf(phi3W[k*FF + col]);
    }
    // pWr1: B-fragment for s = [cnt, a1..a15, 0..0] @ [br1; Wr1] ; 8 coltiles, 1 kt (K=32)
    if (i < 8*64*8){
        int e = i&7, l=(i>>3)&63, c = i>>9;
        int col = c*16 + (l&15);
        int k = (l>>4)*8 + e;
        float v = 0.f;
        if (k == 0) v = br1[col];
        else if (k < 16) v = Wr1[(k-1)*DD + col];
        pWr1[i] = f2bf(v);
    }
}

// ---------------- fused per-node features: VN1/2/3 + phi1(hp) + phi2(hpp) + phi3*vn3(vp) ----------------
__global__ __launch_bounds__(512) void k_node(
    const float* __restrict__ hA, const float* __restrict__ vA,
    const float* __restrict__ vn1W, const float* __restrict__ vn1U,
    const float* __restrict__ vn2W, const float* __restrict__ vn2U,
    const float* __restrict__ vn3W, const float* __restrict__ vn3U,
    const unsigned short* __restrict__ pPhi1, const float* __restrict__ phi1b,
    const unsigned short* __restrict__ pPhi2, const float* __restrict__ phi2b,
    const unsigned short* __restrict__ pPhi3, const float* __restrict__ phi3b,
    float* __restrict__ hpO, float* __restrict__ hppO, float* __restrict__ vpO)
{
    __shared__ unsigned short sH[64*128];
    __shared__ unsigned short sE[64*64];
    __shared__ float sVA[64*48];
    __shared__ float sO3[64*16*3];
    __shared__ float sW[6*256];
    int tid = threadIdx.x;
    int n0 = blockIdx.x*64;

    #pragma unroll
    for (int it = 0; it < 2; ++it){
        int c = tid + it*512;
        int row = c >> 4, cb = c & 15;
        int gn = n0 + row; if (gn > NN-1) gn = NN-1;
        const float* p = hA + (size_t)gn*DD + cb*8;
        float4 f0 = *(const float4*)p;
        float4 f1 = *(const float4*)(p+4);
        uint4 u;
        u.x = pack2(f0.x,f0.y); u.y = pack2(f0.z,f0.w);
        u.z = pack2(f1.x,f1.y); u.w = pack2(f1.z,f1.w);
        *(uint4*)&sH[row*128 + ((cb ^ (row&7))*8)] = u;
    }
    #pragma unroll
    for (int it = 0; it < 6; ++it){
        int i = tid + it*512;
        int row = i/48, cc = i%48;
        int gn = n0 + row; if (gn > NN-1) gn = NN-1;
        sVA[i] = vA[(size_t)gn*48 + cc];
    }
    #pragma unroll
    for (int it = 0; it < 3; ++it){
        int i = tid + it*512;
        float v;
        if      (i <  256) v = vn1W[i];
        else if (i <  512) v = vn1U[i-256];
        else if (i <  768) v = vn2W[i-512];
        else if (i < 1024) v = vn2U[i-768];
        else if (i < 1280) v = vn3W[i-1024];
        else               v = vn3U[i-1280];
        sW[i] = v;
    }
    {
        uint2* z = (uint2*)sE;
        z[tid] = make_uint2(0u,0u);
        z[tid+512] = make_uint2(0u,0u);
    }
    __syncthreads();

    #pragma unroll
    for (int it = 0; it < 2; ++it){
        int item = tid + it*512;
        int nl = item >> 4, g = item & 15;
        const float* v = &sVA[nl*48];
        float q0[3]={0,0,0}, q1[3]={0,0,0}, q2[3]={0,0,0};
        float c0[3]={0,0,0}, c1[3]={0,0,0}, c2[3]={0,0,0};
        #pragma unroll
        for (int ff = 0; ff < FF; ++ff){
            int fi = (ff + g) & 15;
            float v0 = v[fi*3], v1 = v[fi*3+1], v2 = v[fi*3+2];
            #pragma unroll
            for (int m = 0; m < 3; ++m){
                float w = sW[m*512 + g*16 + fi];
                float u = sW[m*512 + 256 + g*16 + fi];
                q0[m] += w*v0; q1[m] += w*v1; q2[m] += w*v2;
                c0[m] += u*v0; c1[m] += u*v1; c2[m] += u*v2;
            }
        }
        #pragma unroll
        for (int m = 0; m < 3; ++m){
            float dot = q0[m]*c0[m] + q1[m]*c1[m] + q2[m]*c2[m];
            float ksq = c0[m]*c0[m] + c1[m]*c1[m] + c2[m]*c2[m] + EPSV;
            float s = dot >= 0.f ? 0.f : dot/ksq;
            float o0 = q0[m]-s*c0[m], o1 = q1[m]-s*c1[m], o2 = q2[m]-s*c2[m];
            if (m < 2){
                float nr = sqrtf(o0*o0+o1*o1+o2*o2) + EPSV;
                int col = (m==0) ? g : (32+g);
                int cb = col>>3;
                sE[nl*64 + ((cb ^ (nl&7))*8) + (col&7)] = f2bf(nr);
            } else {
                float* o = &sO3[(nl*16+g)*3];
                o[0]=o0; o[1]=o1; o[2]=o2;
            }
        }
    }
    __syncthreads();

    int wv = tid>>6, l = tid&63, lr = l&15, lg = l>>4;

    f32x4 a1[4];
    #pragma unroll
    for (int rt = 0; rt < 4; ++rt) a1[rt] = (f32x4){0.f,0.f,0.f,0.f};
    for (int kt = 0; kt < 4; ++kt){
        bf16x8 b = ld8(pPhi1 + ((size_t)(wv*5+kt)*64 + l)*8);
        #pragma unroll
        for (int rt = 0; rt < 4; ++rt){
            int row = rt*16 + lr;
            bf16x8 a = ld8(&sH[row*128 + (((kt*4+lg) ^ (row&7))*8)]);
            a1[rt] = __builtin_amdgcn_mfma_f32_16x16x32_bf16(a, b, a1[rt], 0, 0, 0);
        }
    }
    {
        bf16x8 b = ld8(pPhi1 + ((size_t)(wv*5+4)*64 + l)*8);
        #pragma unroll
        for (int rt = 0; rt < 4; ++rt){
            int row = rt*16 + lr;
            bf16x8 a = ld8(&sE[row*64 + ((lg ^ (row&7))*8)]);
            a1[rt] = __builtin_amdgcn_mfma_f32_16x16x32_bf16(a, b, a1[rt], 0, 0, 0);
        }
    }
    f32x4 a23 = (f32x4){0.f,0.f,0.f,0.f};
    if (wv < 4){
        int row = wv*16 + lr;
        for (int kt = 0; kt < 4; ++kt){
            bf16x8 b = ld8(pPhi3 + ((size_t)kt*64 + l)*8);
            bf16x8 a = ld8(&sH[row*128 + (((kt*4+lg) ^ (row&7))*8)]);
            a23 = __builtin_amdgcn_mfma_f32_16x16x32_bf16(a, b, a23, 0, 0, 0);
        }
    } else {
        int row = (wv-4)*16 + lr;
        for (int kt = 0; kt < 4; ++kt){
            bf16x8 b = ld8(pPhi2 + ((size_t)kt*64 + l)*8);
            bf16x8 a = ld8(&sH[row*128 + (((kt*4+lg) ^ (row&7))*8)]);
            a23 = __builtin_amdgcn_mfma_f32_16x16x32_bf16(a, b, a23, 0, 0, 0);
        }
        {
            bf16x8 b = ld8(pPhi2 + ((size_t)4*64 + l)*8);
            bf16x8 a = ld8(&sE[row*64 + (((4+lg) ^ (row&7))*8)]);
            a23 = __builtin_amdgcn_mfma_f32_16x16x32_bf16(a, b, a23, 0, 0, 0);
        }
    }

    {
        int col = wv*16 + lr;
        float b1 = phi1b[col];
        #pragma unroll
        for (int rt = 0; rt < 4; ++rt){
            #pragma unroll
            for (int r4 = 0; r4 < 4; ++r4){
                int n = n0 + rt*16 + lg*4 + r4;
                if (n < NN) hpO[(size_t)n*DD + col] = lrelu(a1[rt][r4] + b1);
            }
        }
    }
    if (wv < 4){
        float b3 = phi3b[lr];
        #pragma unroll
        for (int r4 = 0; r4 < 4; ++r4){
            int nl = wv*16 + lg*4 + r4;
            int n = n0 + nl;
            float gate = lrelu(a23[r4] + b3);
            if (n < NN){
                const float* o = &sO3[(nl*16+lr)*3];
                float* vo = vpO + (size_t)n*48 + lr*3;
                vo[0] = o[0]*gate; vo[1] = o[1]*gate; vo[2] = o[2]*gate;
            }
        }
    } else {
        float b2 = phi2b[lr];
        #pragma unroll
        for (int r4 = 0; r4 < 4; ++r4){
            int nl = (wv-4)*16 + lg*4 + r4;
            int n = n0 + nl;
            if (n < NN) hppO[(size_t)n*FF + lr] = lrelu(a23[r4] + b2);
        }
    }
}

// ---------------- kk/vv of h_B in MFMA B-fragment packed bf16 ----------------
__global__ __launch_bounds__(128) void k_kv(
    const float* __restrict__ hB, const float* __restrict__ Wk,
    const float* __restrict__ Wv, const float* __restrict__ bv,
    unsigned short* __restrict__ pKK, unsigned short* __restrict__ pVV)
{
    __shared__ float sB[DD];
    int b = blockIdx.x, j = threadIdx.x;
    sB[j] = hB[(size_t)b*DD + j];
    __syncthreads();
    float ak = 0.f, av = bv[j];
    for (int i = 0; i < DD; ++i){
        float h = sB[i];
        ak += h*Wk[i*DD+j];
        av += h*Wv[i*DD+j];
    }
    {
        int c = b>>4, lr = b&15, kt = j>>5, lg = (j>>3)&3, e = j&7;
        pKK[((c*4+kt)*64 + lg*16 + lr)*8 + e] = f2bf(lrelu(ak));
    }
    {
        int kt = b>>5, lg = (b>>3)&3, e = b&7, c = j>>4, lr = j&15;
        pVV[((c*8+kt)*64 + lg*16 + lr)*8 + e] = f2bf(av);
    }
}

// ---------------- fused cross-attention via bf16 MFMA ----------------
__global__ __launch_bounds__(512, 4) void k_attn_mfma(
    const float* __restrict__ hA, const unsigned short* __restrict__ pWq,
    const unsigned short* __restrict__ pKK, const unsigned short* __restrict__ pVV,
    const float* __restrict__ mask, float* __restrict__ attnO)
{
    __shared__ unsigned short sU[64*256];
    __shared__ float sMx[64][2];
    __shared__ float sSm[64][2];
    unsigned short* sX = sU;
    unsigned short* sQ = sU + 64*128;
    unsigned short* sP = sU;
    int tid = threadIdx.x;
    int n0 = blockIdx.x*64;

    #pragma unroll
    for (int it = 0; it < 2; ++it){
        int c = tid + it*512;
        int row = c >> 4, cb = c & 15;
        int gn = n0 + row; if (gn > NN-1) gn = NN-1;
        const float* srcp = hA + (size_t)gn*DD + cb*8;
        float4 f0 = *(const float4*)srcp;
        float4 f1 = *(const float4*)(srcp+4);
        uint4 u;
        u.x = pack2(f0.x,f0.y); u.y = pack2(f0.z,f0.w);
        u.z = pack2(f1.x,f1.y); u.w = pack2(f1.z,f1.w);
        *(uint4*)&sX[row*128 + ((cb ^ (row&7))*8)] = u;
    }
    __syncthreads();

    int wv = tid>>6, l = tid&63, lr = l&15, lg = l>>4;
    int rw = wv>>1, chh = wv&1;
    int rowA = rw*16 + lr;

    {
        f32x4 q[4];
        #pragma unroll
        for (int c = 0; c < 4; ++c) q[c] = (f32x4){0.f,0.f,0.f,0.f};
        for (int kt = 0; kt < 4; ++kt){
            bf16x8 a = ld8(&sX[rowA*128 + (((kt*4+lg) ^ (rowA&7))*8)]);
            #pragma unroll
            for (int c = 0; c < 4; ++c){
                bf16x8 b = ld8(pWq + (size_t)(((chh*4+c)*4 + kt)*512) + l*8);
                q[c] = __builtin_amdgcn_mfma_f32_16x16x32_bf16(a, b, q[c], 0, 0, 0);
            }
        }
        __syncthreads();
        #pragma unroll
        for (int c = 0; c < 4; ++c)
        #pragma unroll
        for (int r4 = 0; r4 < 4; ++r4){
            int row = rw*16 + lg*4 + r4;
            int col = chh*64 + c*16 + lr;
            int cb = col>>3;
            sQ[row*128 + ((cb ^ (row&7))*8) + (col&7)] = f2bf(lrelu(q[c][r4]));
        }
    }
    __syncthreads();

    f32x4 S[8];
    #pragma unroll
    for (int cl = 0; cl < 8; ++cl) S[cl] = (f32x4){0.f,0.f,0.f,0.f};
    for (int kt = 0; kt < 4; ++kt){
        bf16x8 a = ld8(&sQ[rowA*128 + (((kt*4+lg) ^ (rowA&7))*8)]);
        #pragma unroll
        for (int cl = 0; cl < 8; ++cl){
            bf16x8 b = ld8(pKK + (size_t)(((chh*8+cl)*4 + kt)*512) + l*8);
            S[cl] = __builtin_amdgcn_mfma_f32_16x16x32_bf16(a, b, S[cl], 0, 0, 0);
        }
    }
    float den[4];
    #pragma unroll
    for (int r4 = 0; r4 < 4; ++r4){
        int row = rw*16 + lg*4 + r4;
        int gn = n0 + row; if (gn > NN-1) gn = NN-1;
        float mx = -1e30f;
        #pragma unroll
        for (int cl = 0; cl < 8; ++cl){
            int col = chh*128 + cl*16 + lr;
            float m = mask[(size_t)gn*NBB + col];
            float s = m*S[cl][r4] - 1000.f*(1.f-m);
            S[cl][r4] = s;
            mx = fmaxf(mx, s);
        }
        mx = fmaxf(mx, __shfl_xor(mx, 1));
        mx = fmaxf(mx, __shfl_xor(mx, 2));
        mx = fmaxf(mx, __shfl_xor(mx, 4));
        mx = fmaxf(mx, __shfl_xor(mx, 8));
        if (lr == 0) sMx[row][chh] = mx;
    }
    __syncthreads();
    #pragma unroll
    for (int r4 = 0; r4 < 4; ++r4){
        int row = rw*16 + lg*4 + r4;
        float m = fmaxf(sMx[row][0], sMx[row][1]);
        float sm = 0.f;
        #pragma unroll
        for (int cl = 0; cl < 8; ++cl){
            float p = expf(S[cl][r4] - m);
            S[cl][r4] = p;
            sm += p;
        }
        sm += __shfl_xor(sm, 1);
        sm += __shfl_xor(sm, 2);
        sm += __shfl_xor(sm, 4);
        sm += __shfl_xor(sm, 8);
        if (lr == 0) sSm[row][chh] = sm;
    }
    __syncthreads();
    #pragma unroll
    for (int r4 = 0; r4 < 4; ++r4){
        int row = rw*16 + lg*4 + r4;
        den[r4] = sSm[row][0] + sSm[row][1];
    }
    #pragma unroll
    for (int cl = 0; cl < 8; ++cl)
    #pragma unroll
    for (int r4 = 0; r4 < 4; ++r4){
        int row = rw*16 + lg*4 + r4;
        int col = chh*128 + cl*16 + lr;
        int cb = col>>3;
        sP[row*256 + ((cb ^ (row&7))*8) + (col&7)] = f2bf(S[cl][r4]);
    }
    __syncthreads();

    f32x4 O[4];
    #pragma unroll
    for (int c = 0; c < 4; ++c) O[c] = (f32x4){0.f,0.f,0.f,0.f};
    for (int kt = 0; kt < 8; ++kt){
        bf16x8 a = ld8(&sP[rowA*256 + (((kt*4+lg) ^ (rowA&7))*8)]);
        #pragma unroll
        for (int c = 0; c < 4; ++c){
            bf16x8 b = ld8(pVV + (size_t)(((chh*4+c)*8 + kt)*512) + l*8);
            O[c] = __builtin_amdgcn_mfma_f32_16x16x32_bf16(a, b, O[c], 0, 0, 0);
        }
    }
    #pragma unroll
    for (int c = 0; c < 4; ++c)
    #pragma unroll
    for (int r4 = 0; r4 < 4; ++r4){
        int row = rw*16 + lg*4 + r4;
        int n = n0 + row;
        if (n < NN){
            int col = chh*64 + c*16 + lr;
            attnO[(size_t)n*DD + col] = O[c][r4] / den[r4];
        }
    }
}

// ---------------- edge phase: counting sort by dst, then per-node gather ----------------
__global__ __launch_bounds__(256) void k_hist(const int* __restrict__ dst, int* __restrict__ deg){
    int e = blockIdx.x*256 + threadIdx.x;
    if (e < EE) atomicAdd(&deg[dst[e]], 1);
}

__global__ __launch_bounds__(256) void k_scan1(const int* __restrict__ deg,
                                               int* __restrict__ excl, int* __restrict__ bsum){
    __shared__ int s[256];
    int tid = threadIdx.x;
    int i = blockIdx.x*256 + tid;
    int v = (i < NN) ? deg[i] : 0;
    s[tid] = v;
    __syncthreads();
    for (int o = 1; o < 256; o <<= 1){
        int t = 0;
        if (tid >= o) t = s[tid-o];
        __syncthreads();
        if (tid >= o) s[tid] += t;
        __syncthreads();
    }
    if (i < NN) excl[i] = s[tid] - v;
    if (tid == 255) bsum[blockIdx.x] = s[255];
}

__global__ __launch_bounds__(256) void k_scan2(const int* __restrict__ bsum,
                                               int* __restrict__ boff, int nb){
    __shared__ int s[256];
    int tid = threadIdx.x;
    int v = (tid < nb) ? bsum[tid] : 0;
    s[tid] = v;
    __syncthreads();
    for (int o = 1; o < 256; o <<= 1){
        int t = 0;
        if (tid >= o) t = s[tid-o];
        __syncthreads();
        if (tid >= o) s[tid] += t;
        __syncthreads();
    }
    if (tid < nb) boff[tid] = s[tid] - v;
}

__global__ __launch_bounds__(256) void k_scan3(const int* __restrict__ excl,
                                               const int* __restrict__ boff,
                                               int* __restrict__ start, int* __restrict__ cursor){
    int i = blockIdx.x*256 + threadIdx.x;
    if (i < NN){
        int st = excl[i] + boff[blockIdx.x];
        start[i] = st;
        cursor[i] = st;
    }
    if (i == 0) start[NN] = EE;
}

__global__ __launch_bounds__(256) void k_scatter(const int* __restrict__ src,
                                                 const int* __restrict__ dst,
                                                 int* __restrict__ cursor, int* __restrict__ esrc){
    int e = blockIdx.x*256 + threadIdx.x;
    if (e >= EE) return;
    int pos = atomicAdd(&cursor[dst[e]], 1);
    esrc[pos] = src[e];
}

// 4 lanes per node, butterfly-reduced
__global__ __launch_bounds__(256) void k_gather(const int* __restrict__ start,
                                                const int* __restrict__ esrc,
                                                const float* __restrict__ xA,
                                                const float* __restrict__ rbf_k,
                                                float* __restrict__ acc)
{
    int gt = blockIdx.x*256 + threadIdx.x;
    int n = gt >> 2, sub = gt & 3;
    if (n >= NN) return;
    float kc = rbf_k[0];
    float xd0 = xA[n*3+0], xd1 = xA[n*3+1], xd2 = xA[n*3+2];
    float a[64];
    #pragma unroll
    for (int i = 0; i < 64; ++i) a[i] = 0.f;
    int b0 = start[n], b1 = start[n+1];
    for (int i = b0 + sub; i < b1; i += 4){
        int s = esrc[i];
        float r0 = xA[s*3+0]-xd0, r1 = xA[s*3+1]-xd1, r2 = xA[s*3+2]-xd2;
        float rn = sqrtf(r0*r0+r1*r1+r2*r2);
        a[0] += 1.f;
        a[16] += r0; a[17] += r1; a[18] += r2;
        #pragma unroll
        for (int q = 0; q < RR; ++q){
            float df = rn - (float)q*CSPACE;
            float rb = expf(-df*df*kc);
            a[1+q] += rb;
            a[19+q*3+0] += rb*r0;
            a[19+q*3+1] += rb*r1;
            a[19+q*3+2] += rb*r2;
        }
    }
    #pragma unroll
    for (int i = 0; i < 64; ++i){
        a[i] += __shfl_xor(a[i], 1);
        a[i] += __shfl_xor(a[i], 2);
    }
    float4* o = (float4*)(acc + (size_t)n*64);
    #pragma unroll
    for (int i = 0; i < 4; ++i){
        int idx = sub*4 + i;
        o[idx] = make_float4(a[4*idx], a[4*idx+1], a[4*idx+2], a[4*idx+3]);
    }
}

// ---------------- GRU via bf16 MFMA; sG via mini-MFMA; residual from LDS ----------------
__global__ __launch_bounds__(512) void k_gru_mfma(
    const float* __restrict__ hA, const float* __restrict__ attn,
    const float* __restrict__ hp, const float* __restrict__ acc,
    const unsigned short* __restrict__ pWr1,
    const unsigned short* __restrict__ pWih, const unsigned short* __restrict__ pWhh,
    const float* __restrict__ bih, const float* __restrict__ bhh,
    float* __restrict__ outNode)
{
    __shared__ unsigned short sX[64*256];
    __shared__ unsigned short sGm[64*128];
    __shared__ unsigned short sM[64*32];    // moments bf16, K padded to 32
    int tid = threadIdx.x;
    int n0 = blockIdx.x*64;

    // ---- stage X = [hA | attn] bf16 swizzled
    #pragma unroll
    for (int it = 0; it < 4; ++it){
        int c = tid + it*512;
        int row = c >> 5, cb = c & 31;
        int gn = n0 + row; if (gn > NN-1) gn = NN-1;
        int k = cb*8;
        const float* srcp = (k < DD) ? (hA + (size_t)gn*DD + k)
                                     : (attn + (size_t)gn*DD + (k-DD));
        float4 f0 = *(const float4*)srcp;
        float4 f1 = *(const float4*)(srcp+4);
        uint4 u;
        u.x = pack2(f0.x,f0.y); u.y = pack2(f0.z,f0.w);
        u.z = pack2(f1.x,f1.y); u.w = pack2(f1.z,f1.w);
        *(uint4*)&sX[row*256 + ((cb ^ (row&7))*8)] = u;
    }
    // ---- stage RBF moments -> sM[row][k] (k<16 real, 16..31 zero), coalesced
    #pragma unroll
    for (int it = 0; it < 4; ++it){
        int i = tid + it*512;
        int row = i >> 5, k = i & 31;
        int gn = n0 + row; if (gn > NN-1) gn = NN-1;
        float v = (k < 16) ? acc[(size_t)gn*64 + k] : 0.f;
        sM[i] = f2bf(v);
    }
    __syncthreads();

    int wv = tid >> 6, l = tid & 63;
    int lr = l & 15, lg = l >> 4;
    int col = wv*16 + lr;

    // ---- sG via mini-MFMA: s = moments @ [br1;Wr1] ; then sGm = hp*s/den
    {
        f32x4 sv[4];
        #pragma unroll
        for (int rt = 0; rt < 4; ++rt) sv[rt] = (f32x4){0.f,0.f,0.f,0.f};
        bf16x8 b = ld8(pWr1 + (size_t)wv*512 + l*8);
        #pragma unroll
        for (int rt = 0; rt < 4; ++rt){
            int row = rt*16 + lr;
            bf16x8 a = ld8(&sM[row*32 + lg*8]);
            sv[rt] = __builtin_amdgcn_mfma_f32_16x16x32_bf16(a, b, sv[rt], 0, 0, 0);
        }
        #pragma unroll
        for (int rt = 0; rt < 4; ++rt){
            #pragma unroll
            for (int r4 = 0; r4 < 4; ++r4){
                int row = rt*16 + lg*4 + r4;
                int gn = n0 + row; if (gn > NN-1) gn = NN-1;
                float cnt = bf2f(sM[row*32]);          // integer count, exact in bf16
                float den = fmaxf(cnt, 1.f);
                float g = hp[(size_t)gn*DD + col] * sv[rt][r4] / den;
                sGm[row*128 + (((col>>3) ^ (row&7))*8) + (col&7)] = f2bf(g);
            }
        }
    }
    __syncthreads();

    // ---- GRU GEMMs
    f32x4 aR[4], aZ[4], aNI[4], aNH[4];
    #pragma unroll
    for (int rt = 0; rt < 4; ++rt){
        aR[rt] = (f32x4){0.f,0.f,0.f,0.f};
        aZ[rt] = (f32x4){0.f,0.f,0.f,0.f};
        aNI[rt] = (f32x4){0.f,0.f,0.f,0.f};
        aNH[rt] = (f32x4){0.f,0.f,0.f,0.f};
    }
    const unsigned short* bR = pWih + ((size_t)(0*8 + wv)*8)*512 + l*8;
    const unsigned short* bZ = pWih + ((size_t)(1*8 + wv)*8)*512 + l*8;
    const unsigned short* bN = pWih + ((size_t)(2*8 + wv)*8)*512 + l*8;
    for (int kt = 0; kt < 8; ++kt){
        bf16x8 br_ = ld8(bR + kt*512);
        bf16x8 bz_ = ld8(bZ + kt*512);
        bf16x8 bn_ = ld8(bN + kt*512);
        #pragma unroll
        for (int rt = 0; rt < 4; ++rt){
            int rowA = rt*16 + lr;
            bf16x8 a = ld8(&sX[rowA*256 + (((kt*4 + lg) ^ (rowA&7))*8)]);
            aR[rt]  = __builtin_amdgcn_mfma_f32_16x16x32_bf16(a, br_, aR[rt], 0, 0, 0);
            aZ[rt]  = __builtin_amdgcn_mfma_f32_16x16x32_bf16(a, bz_, aZ[rt], 0, 0, 0);
            aNI[rt] = __builtin_amdgcn_mfma_f32_16x16x32_bf16(a, bn_, aNI[rt], 0, 0, 0);
        }
    }
    const unsigned short* cR = pWhh + ((size_t)(0*8 + wv)*4)*512 + l*8;
    const unsigned short* cZ = pWhh + ((size_t)(1*8 + wv)*4)*512 + l*8;
    const unsigned short* cN = pWhh + ((size_t)(2*8 + wv)*4)*512 + l*8;
    for (int kt = 0; kt < 4; ++kt){
        bf16x8 br_ = ld8(cR + kt*512);
        bf16x8 bz_ = ld8(cZ + kt*512);
        bf16x8 bn_ = ld8(cN + kt*512);
        #pragma unroll
        for (int rt = 0; rt < 4; ++rt){
            int rowA = rt*16 + lr;
            bf16x8 a = ld8(&sGm[rowA*128 + (((kt*4 + lg) ^ (rowA&7))*8)]);
            aR[rt]  = __builtin_amdgcn_mfma_f32_16x16x32_bf16(a, br_, aR[rt], 0, 0, 0);
            aZ[rt]  = __builtin_amdgcn_mfma_f32_16x16x32_bf16(a, bz_, aZ[rt], 0, 0, 0);
            aNH[rt] = __builtin_amdgcn_mfma_f32_16x16x32_bf16(a, bn_, aNH[rt], 0, 0, 0);
        }
    }

    // ---- epilogue: gates + residual (h from sX bf16 in LDS)
    float b_r = bih[col] + bhh[col];
    float b_z = bih[DD+col] + bhh[DD+col];
    float b_ni = bih[2*DD+col];
    float b_nh = bhh[2*DD+col];
    #pragma unroll
    for (int rt = 0; rt < 4; ++rt){
        #pragma unroll
        for (int r4 = 0; r4 < 4; ++r4){
            int nl = rt*16 + lg*4 + r4;
            int n = n0 + nl;
            if (n < NN){
                float rg = sigmoidf_(aR[rt][r4] + b_r);
                float zg = sigmoidf_(aZ[rt][r4] + b_z);
                float ng = tanhf(aNI[rt][r4] + b_ni + rg*(aNH[rt][r4] + b_nh));
                float sg = bf2f(sGm[nl*128 + (((col>>3) ^ (nl&7))*8) + (col&7)]);
                float h = bf2f(sX[nl*256 + (((col>>3) ^ (nl&7))*8) + (col&7)]);
                outNode[(size_t)n*DD + col] = h + (1.f-zg)*ng + zg*sg;
            }
        }
    }
}

// ---------------- vector update: agg_v inline, VN-MLP, residual ----------------
__global__ __launch_bounds__(256) void k_vec(
    const float* __restrict__ vA, const float* __restrict__ vp,
    const float* __restrict__ hpp, const float* __restrict__ acc,
    const float* __restrict__ Wr2, const float* __restrict__ br2,
    const float* __restrict__ Wr3, const float* __restrict__ br3,
    const float* __restrict__ W1, const float* __restrict__ U1,
    const float* __restrict__ W2, float* __restrict__ outV)
{
    __shared__ float sW1[32*32], sU1[32*32], sW2[16*32];
    __shared__ float sWr2[RR*FF], sWr3[RR*FF];
    __shared__ float sVin[8][32][3];
    __shared__ float sVh[8][32][3];
    __shared__ float sAcc[8][64];
    __shared__ float sVA[8][48];
    int tid = threadIdx.x;
    for (int i = tid; i < 1024; i += 256){ sW1[i]=W1[i]; sU1[i]=U1[i]; }
    for (int i = tid; i < 512; i += 256) sW2[i]=W2[i];
    for (int i = tid; i < RR*FF; i += 256){ sWr2[i]=Wr2[i]; sWr3[i]=Wr3[i]; }
    int n0 = blockIdx.x*8;
    for (int i = tid; i < 8*64; i += 256) sAcc[i/64][i%64] = acc[(size_t)n0*64 + i];
    for (int i = tid; i < 8*48; i += 256) sVA[i/48][i%48] = vA[(size_t)n0*48 + i];
    __syncthreads();
    int t = tid >> 5, g = tid & 31;
    int n = n0 + t;
    if (g < 16){
        int f = g;
        float cnt = sAcc[t][0];
        float den = fmaxf(cnt, 1.f);
        float s1 = cnt*br2[f];
        #pragma unroll
        for (int r = 0; r < RR; ++r) s1 += sAcc[t][1+r]*sWr2[r*FF+f];
        float hpv = hpp[(size_t)n*FF+f];
        float b3 = br3[f];
        #pragma unroll
        for (int c = 0; c < 3; ++c){
            float s2 = b3*sAcc[t][16+c];
            #pragma unroll
            for (int r = 0; r < RR; ++r) s2 += sAcc[t][19+r*3+c]*sWr3[r*FF+f];
            float aggv = (vp[(size_t)n*48 + f*3 + c]*s1 + hpv*s2)/den;
            sVin[t][FF+f][c] = aggv;
            sVin[t][f][c] = sVA[t][f*3+c];
        }
    }
    __syncthreads();
    {
        float q0=0,q1=0,q2=0,k0=0,k1=0,k2=0;
        #pragma unroll
        for (int ff = 0; ff < 32; ++ff){
            int f = (ff + g) & 31;
            float w = sW1[g*32+f], u = sU1[g*32+f];
            float v0=sVin[t][f][0], v1=sVin[t][f][1], v2=sVin[t][f][2];
            q0+=w*v0;q1+=w*v1;q2+=w*v2;
            k0+=u*v0;k1+=u*v1;k2+=u*v2;
        }
        float dot=q0*k0+q1*k1+q2*k2;
        float ksq=k0*k0+k1*k1+k2*k2+EPSV;
        float s = dot>=0.f?0.f:dot/ksq;
        sVh[t][g][0]=q0-s*k0; sVh[t][g][1]=q1-s*k1; sVh[t][g][2]=q2-s*k2;
    }
    __syncthreads();
    if (g < 16){
        float o0=sVA[t][g*3+0], o1=sVA[t][g*3+1], o2=sVA[t][g*3+2];
        #pragma unroll
        for (int ff = 0; ff < 32; ++ff){
            int f = (ff + g) & 31;
            float w = sW2[g*32+f];
            o0 += w*sVh[t][f][0];
            o1 += w*sVh[t][f][1];
            o2 += w*sVh[t][f][2];
        }
        outV[(size_t)n*48 + g*3 + 0] = o0;
        outV[(size_t)n*48 + g*3 + 1] = o1;
        outV[(size_t)n*48 + g*3 + 2] = o2;
    }
}

extern "C" void kernel_launch(void* const* d_in, const int* in_sizes, int n_in,
                              void* d_out, int out_size, void* d_ws, size_t ws_size,
                              hipStream_t stream)
{
    const float* hA   = (const float*)d_in[0];
    const float* vA   = (const float*)d_in[1];
    const float* xA   = (const float*)d_in[2];
    const float* hB   = (const float*)d_in[3];
    const float* mask = (const float*)d_in[4];
    const int*   src  = (const int*)d_in[5];
    const int*   dst  = (const int*)d_in[6];
    const float* rbfk = (const float*)d_in[7];
    const float* Wr1  = (const float*)d_in[8];
    const float* br1  = (const float*)d_in[9];
    const float* Wr2  = (const float*)d_in[10];
    const float* br2  = (const float*)d_in[11];
    const float* Wr3  = (const float*)d_in[12];
    const float* br3  = (const float*)d_in[13];
    const float* vn1W = (const float*)d_in[14];
    const float* vn1U = (const float*)d_in[15];
    const float* vn2W = (const float*)d_in[16];
    const float* vn2U = (const float*)d_in[17];
    const float* vn3W = (const float*)d_in[18];
    const float* vn3U = (const float*)d_in[19];
    const float* phi1W= (const float*)d_in[20];
    const float* phi1b= (const float*)d_in[21];
    const float* phi2W= (const float*)d_in[22];
    const float* phi2b= (const float*)d_in[23];
    const float* phi3W= (const float*)d_in[24];
    const float* phi3b= (const float*)d_in[25];
    const float* Wq   = (const float*)d_in[26];
    const float* Wk   = (const float*)d_in[27];
    const float* Wv   = (const float*)d_in[28];
    const float* bv   = (const float*)d_in[29];
    const float* Wih  = (const float*)d_in[30];
    const float* Whh  = (const float*)d_in[31];
    const float* bih  = (const float*)d_in[32];
    const float* bhh  = (const float*)d_in[33];
    const float* W1   = (const float*)d_in[34];
    const float* U1   = (const float*)d_in[35];
    const float* W2   = (const float*)d_in[36];

    float* ws = (float*)d_ws;
    float* hp     = ws;  ws += (size_t)NN*DD;
    float* hpp    = ws;  ws += (size_t)NN*FF;
    float* vp     = ws;  ws += (size_t)NN*FF*3;
    float* attn   = ws;  ws += (size_t)NN*DD;
    float* acc    = ws;  ws += (size_t)NN*64;
    unsigned short* pWih = (unsigned short*)ws; ws += (size_t)3*8*8*512/2;
    unsigned short* pWhh = (unsigned short*)ws; ws += (size_t)3*8*4*512/2;
    unsigned short* pWq  = (unsigned short*)ws; ws += (size_t)8*4*512/2;
    unsigned short* pKK  = (unsigned short*)ws; ws += (size_t)16*4*512/2;
    unsigned short* pVV  = (unsigned short*)ws; ws += (size_t)8*8*512/2;
    unsigned short* pPhi1= (unsigned short*)ws; ws += (size_t)8*5*512/2;
    unsigned short* pPhi2= (unsigned short*)ws; ws += (size_t)5*512/2;
    unsigned short* pPhi3= (unsigned short*)ws; ws += (size_t)4*512/2;
    unsigned short* pWr1 = (unsigned short*)ws; ws += (size_t)8*512/2;
    int* deg    = (int*)ws;  ws += NN;
    int* excl   = (int*)ws;  ws += NN;
    int* bsum   = (int*)ws;  ws += 256;
    int* boff   = (int*)ws;  ws += 256;
    int* startN = (int*)ws;  ws += NN+1;
    int* cursor = (int*)ws;  ws += NN;
    int* esrc   = (int*)ws;  ws += EE;

    float* outV = (float*)d_out;
    float* outH = (float*)d_out + (size_t)NN*FF*3;

    const int NB_SCAN = (NN + 255)/256;

    hipMemsetAsync(deg, 0, (size_t)NN*sizeof(int), stream);
    k_prep<<<384, 256, 0, stream>>>(Wih, Whh, Wq, phi1W, phi2W, phi3W, Wr1, br1,
                                    pWih, pWhh, pWq, pPhi1, pPhi2, pPhi3, pWr1);
    k_hist<<<(EE+255)/256, 256, 0, stream>>>(dst, deg);
    k_scan1<<<NB_SCAN, 256, 0, stream>>>(deg, excl, bsum);
    k_scan2<<<1, 256, 0, stream>>>(bsum, boff, NB_SCAN);
    k_scan3<<<NB_SCAN, 256, 0, stream>>>(excl, boff, startN, cursor);
    k_scatter<<<(EE+255)/256, 256, 0, stream>>>(src, dst, cursor, esrc);
    k_gather<<<(NN*4+255)/256, 256, 0, stream>>>(startN, esrc, xA, rbfk, acc);
    k_node<<<(NN+63)/64, 512, 0, stream>>>(hA, vA, vn1W, vn1U, vn2W, vn2U, vn3W, vn3U,
                                           pPhi1, phi1b, pPhi2, phi2b, pPhi3, phi3b,
                                           hp, hpp, vp);
    k_kv<<<NBB, 128, 0, stream>>>(hB, Wk, Wv, bv, pKK, pVV);
    k_attn_mfma<<<(NN+63)/64, 512, 0, stream>>>(hA, pWq, pKK, pVV, mask, attn);
    k_gru_mfma<<<(NN+63)/64, 512, 0, stream>>>(hA, attn, hp, acc, pWr1,
                                               pWih, pWhh, bih, bhh, outH);
    k_vec<<<NN/8, 256, 0, stream>>>(vA, vp, hpp, acc, Wr2, br2, Wr3, br3, W1, U1, W2, outV);
}